// Round 12
// baseline (1055.354 us; speedup 1.0000x reference)
//
#include <hip/hip_runtime.h>
#include <hip/hip_bf16.h>
#include <math.h>

typedef __attribute__((ext_vector_type(8))) short short8;
typedef __attribute__((ext_vector_type(4))) short short4v;
typedef __attribute__((ext_vector_type(8))) __bf16 bf16x8;
typedef __attribute__((ext_vector_type(4))) float f32x4;
typedef unsigned short ushort;
typedef unsigned int uint;

#define DEVI static __device__ __forceinline__

DEVI ushort f2bf(float f) {
  union { float f; unsigned u; } v; v.f = f;
  unsigned r = v.u + 0x7fffu + ((v.u >> 16) & 1u);
  return (ushort)(r >> 16);
}
DEVI float bf2f(ushort h) {
  union { unsigned u; float f; } v; v.u = (unsigned)h << 16; return v.f;
}
DEVI void gload16(const void* g, void* l) {
  __builtin_amdgcn_global_load_lds((const __attribute__((address_space(1))) void*)g,
                                   (__attribute__((address_space(3))) void*)l, 16, 0, 0);
}

// Block-order mapping: XCD swizzle, then row-major / m-stripe / n-band.
DEVI void map_block(int gx, int gy, int BM, int bmode, int& n0, int& m0) {
  const int nwg = gx * gy;
  const int orig = blockIdx.y * gx + blockIdx.x;
  const int qq = nwg >> 3, rr = nwg & 7;
  const int xcd = orig & 7, sidx = orig >> 3;
  const int wg = (xcd < rr ? xcd * (qq + 1) : rr * (qq + 1) + (xcd - rr) * qq) + sidx;
  if (bmode == 0) {
    n0 = (wg % gx) * 128; m0 = (wg / gx) * BM;
  } else if (bmode > 0) {
    const int mh = bmode, bs = gx * mh;
    const int band = wg / bs, wi = wg - band * bs;
    n0 = (wi / mh) * 128;
    m0 = (band * mh + wi % mh) * BM;
  } else {
    const int bn = -bmode, gm = gy, bs = bn * gm;
    const int band = wg / bs, wi = wg - band * bs;
    m0 = (wi / bn) * BM;
    n0 = (band * bn + wi % bn) * 128;
  }
}

// ---------------------------------------------------------------------------
// BMx128 bf16 MFMA GEMM, BK=64. A [M,K] bf16, B [N,K] bf16 (B^T).
// EPI: 1=bf16 store, 2=GELU->bf16, 3=f32 residual add (scalar, sector-aligned),
//      4=f32 NT store (quarter-tile LDS transpose; Cs aliased onto As -> 32KB LDS).
// ---------------------------------------------------------------------------
template<int BM, int EPI>
__global__ __launch_bounds__(256) void gemmT(
    const ushort* __restrict__ A, const ushort* __restrict__ B,
    void* __restrict__ Cv, const float* __restrict__ bias,
    int K, int lda, int ldb, int ldc, float scale, int bmode)
{
  constexpr int BK = 64;
  constexpr int MF = (BM + 31) / 32;
  constexpr int MH = BM / 2;
  constexpr int ACH = BM * BK / 2048;
  constexpr int BCH = 128 * BK / 2048;
  __shared__ ushort As[BM * BK];
  __shared__ ushort Bs[128 * BK];

  int n0, m0;
  map_block(gridDim.x, gridDim.y, BM, bmode, n0, m0);

  const int tid = threadIdx.x;
  const int lane = tid & 63, wv = tid >> 6;
  const int wm = wv >> 1, wn = wv & 1;
  const int l16 = lane & 15, lq = lane >> 4;

  f32x4 acc[MF][4];
#pragma unroll
  for (int i = 0; i < MF; i++)
#pragma unroll
    for (int j = 0; j < 4; j++) acc[i][j] = (f32x4){0.f, 0.f, 0.f, 0.f};

  const char* apS[ACH]; const char* bpS[BCH];
#pragma unroll
  for (int s = 0; s < ACH; s++) {
    int c = tid + 256 * s;
    apS[s] = (const char*)(A + (long)(m0 + (c >> 3)) * lda) + ((c & 7) << 4);
  }
#pragma unroll
  for (int s = 0; s < BCH; s++) {
    int c = tid + 256 * s;
    bpS[s] = (const char*)(B + (long)(n0 + (c >> 3)) * ldb) + ((c & 7) << 4);
  }

  for (int k0 = 0; k0 < K; k0 += BK) {
    const long kb = (long)k0 * 2;
#pragma unroll
    for (int s = 0; s < ACH; s++) gload16(apS[s] + kb, (char*)As + (tid + 256*s) * 16);
#pragma unroll
    for (int s = 0; s < BCH; s++) gload16(bpS[s] + kb, (char*)Bs + (tid + 256*s) * 16);
    __syncthreads();
#pragma unroll
    for (int ks = 0; ks < 2; ks++) {
      bf16x8 af[MF], bfr[4];
#pragma unroll
      for (int i = 0; i < MF; i++)
        af[i] = __builtin_bit_cast(bf16x8, *(const short8*)&As[(wm*MH + i*16 + l16)*BK + ks*32 + lq*8]);
#pragma unroll
      for (int j = 0; j < 4; j++)
        bfr[j] = __builtin_bit_cast(bf16x8, *(const short8*)&Bs[(wn*64 + j*16 + l16)*BK + ks*32 + lq*8]);
#pragma unroll
      for (int i = 0; i < MF; i++)
#pragma unroll
        for (int j = 0; j < 4; j++)
          acc[i][j] = __builtin_amdgcn_mfma_f32_16x16x32_bf16(af[i], bfr[j], acc[i][j], 0, 0, 0);
    }
    __syncthreads();
  }

  float* Cf = (float*)Cv;
  ushort* Ch = (ushort*)Cv;

  if (EPI == 4) {
    // quarter-tile (16 rows) LDS transpose; NT f32x4 stores, 512B/row contiguous.
    // Cs aliased onto As (dead after final barrier): needs 16*132*4 = 8448 B <= 16KB.
    float* Cs = (float*)As;
    const int er = tid >> 5, ec = (tid & 31) << 2;
#pragma unroll
    for (int half = 0; half < 2; half++)
#pragma unroll
      for (int i = 0; i < MF; i++) {
        __syncthreads();
        if (wm == half) {
#pragma unroll
          for (int j = 0; j < 4; j++) {
            const int col = wn*64 + j*16 + l16;
            const float cb = bias ? bias[n0 + col] : 0.f;
#pragma unroll
            for (int t = 0; t < 4; t++)
              Cs[(lq*4 + t)*132 + col] = acc[i][j][t] * scale + cb;
          }
        }
        __syncthreads();
#pragma unroll
        for (int ps = 0; ps < 2; ps++) {
          const int row = ps*8 + er;
          f32x4 v = *(const f32x4*)&Cs[row*132 + ec];
          __builtin_nontemporal_store(v,
              (f32x4*)(Cf + (long)(m0 + half*MH + i*16 + row) * ldc + n0 + ec));
        }
      }
  } else {
#pragma unroll
    for (int i = 0; i < MF; i++) {
      const int row0 = m0 + wm*MH + i*16 + lq*4;
#pragma unroll
      for (int j = 0; j < 4; j++) {
        const int col = n0 + wn*64 + j*16 + l16;
        const float cb = bias ? bias[col] : 0.f;
#pragma unroll
        for (int t = 0; t < 4; t++) {
          float val = acc[i][j][t] * scale + cb;
          const long idx = (long)(row0 + t) * ldc + col;
          if (EPI == 1)      Ch[idx] = f2bf(val);
          else if (EPI == 2) { val = 0.5f * val * (1.f + erff(val * 0.70710678118654752f)); Ch[idx] = f2bf(val); }
          else               Cf[idx] += val;
        }
      }
    }
  }
}

// ---------------------------------------------------------------------------
// Mega GEMM (BK=64): A=nrm [4096,512], B=Bcat[l] [5376,512]. Grid (42,32).
// ---------------------------------------------------------------------------
__global__ __launch_bounds__(256) void megag1(
    const ushort* __restrict__ A, const ushort* __restrict__ B,
    float* __restrict__ finb, ushort* __restrict__ qkh, ushort* __restrict__ XAb,
    const float* __restrict__ gate, const float* __restrict__ qkbias)
{
  constexpr int BK = 64;
  __shared__ ushort As[128 * BK];
  __shared__ ushort Bs[128 * BK];
  int n0, m0;
  map_block(gridDim.x, gridDim.y, 128, 8, n0, m0);

  const int tid = threadIdx.x;
  const int lane = tid & 63, wv = tid >> 6;
  const int wm = wv >> 1, wn = wv & 1;
  const int l16 = lane & 15, lq = lane >> 4;

  f32x4 acc[4][4];
#pragma unroll
  for (int i = 0; i < 4; i++)
#pragma unroll
    for (int j = 0; j < 4; j++) acc[i][j] = (f32x4){0.f, 0.f, 0.f, 0.f};

  const char* apS[4]; const char* bpS[4];
#pragma unroll
  for (int s = 0; s < 4; s++) {
    int c = tid + 256 * s;
    apS[s] = (const char*)(A + (long)(m0 + (c >> 3)) * 512) + ((c & 7) << 4);
    bpS[s] = (const char*)(B + (long)(n0 + (c >> 3)) * 512) + ((c & 7) << 4);
  }

  for (int k0 = 0; k0 < 512; k0 += BK) {
    const long kb = (long)k0 * 2;
#pragma unroll
    for (int s = 0; s < 4; s++) {
      gload16(apS[s] + kb, (char*)As + (tid + 256*s) * 16);
      gload16(bpS[s] + kb, (char*)Bs + (tid + 256*s) * 16);
    }
    __syncthreads();
#pragma unroll
    for (int ks = 0; ks < 2; ks++) {
      bf16x8 af[4], bfr[4];
#pragma unroll
      for (int i = 0; i < 4; i++) {
        af[i]  = __builtin_bit_cast(bf16x8, *(const short8*)&As[(wm*64 + i*16 + l16)*BK + ks*32 + lq*8]);
        bfr[i] = __builtin_bit_cast(bf16x8, *(const short8*)&Bs[(wn*64 + i*16 + l16)*BK + ks*32 + lq*8]);
      }
#pragma unroll
      for (int i = 0; i < 4; i++)
#pragma unroll
        for (int j = 0; j < 4; j++)
          acc[i][j] = __builtin_amdgcn_mfma_f32_16x16x32_bf16(af[i], bfr[j], acc[i][j], 0, 0, 0);
    }
    __syncthreads();
  }

#pragma unroll
  for (int i = 0; i < 4; i++) {
    const int row0 = m0 + wm*64 + i*16 + lq*4;
#pragma unroll
    for (int j = 0; j < 4; j++) {
      const int col = n0 + wn*64 + j*16 + l16;
      if (col < 256) {
        const float g = gate[col];
#pragma unroll
        for (int t = 0; t < 4; t++) finb[(long)(row0 + t) * 256 + col] = acc[i][j][t] * g;
      } else if (col < 1280) {
        const int c = col - 256;
        const float bb = qkbias[c];
#pragma unroll
        for (int t = 0; t < 4; t++) qkh[(long)(row0 + t) * 1024 + c] = f2bf(acc[i][j][t] + bb);
      } else {
        const int c = col - 1280;
#pragma unroll
        for (int t = 0; t < 4; t++) XAb[(long)(row0 + t) * 4096 + c] = f2bf(acc[i][j][t]);
      }
    }
  }
}

// ---------------------------------------------------------------------------
// Fused causal flash attention, balanced q-tile pairs {p, 15-p} per block.
// Grid (8, 32). Double-buffered K/V staging.
// ---------------------------------------------------------------------------
__global__ __launch_bounds__(256) void flash_kernel(
    const ushort* __restrict__ qk, const ushort* __restrict__ v,
    ushort* __restrict__ o)
{
  __shared__ ushort Ks[2][4096];
  __shared__ ushort VTs[2][4096];
  __shared__ ushort Ps[4096];
  const int p = blockIdx.x, bh = blockIdx.y;
  const int b = bh >> 3, h = bh & 7;
  const int tid = threadIdx.x, lane = tid & 63, w = tid >> 6;
  const int l16 = lane & 15, lq = lane >> 4;
  const long tokbase = (long)b * 1024;
  const ushort* Qbase = qk + tokbase * 1024 + h * 64;
  const char*   Kbase = (const char*)(qk + tokbase * 1024 + 512 + h * 64);
  const ushort* Vbase = v + tokbase * 512 + h * 64;

  const int krow = tid >> 3, kcb = (tid & 7) << 4;
  const int vkv  = tid >> 2, vdb = (tid & 3) << 4;
  const int kswz = kcb ^ ((krow & 7) << 4);

#pragma unroll 1
  for (int half = 0; half < 2; half++) {
    const int qt = half ? (15 - p) : p;
    const int q0 = qt * 64;
    const int ntiles = qt + 1;

    const ushort* qrow = Qbase + (long)(q0 + w*16 + l16) * 1024;
    const bf16x8 qf0 = *(const bf16x8*)(qrow + lq*8);
    const bf16x8 qf1 = *(const bf16x8*)(qrow + 32 + lq*8);

    float m_[4] = {-1e30f, -1e30f, -1e30f, -1e30f};
    float l_[4] = {0.f, 0.f, 0.f, 0.f};
    f32x4 od[4];
#pragma unroll
    for (int dt = 0; dt < 4; dt++) od[dt] = (f32x4){0.f, 0.f, 0.f, 0.f};

    gload16(Kbase + (long)krow * 2048 + kswz, (char*)Ks[0] + tid * 16);
    gload16(Kbase + (long)(32 + krow) * 2048 + kswz, (char*)Ks[0] + 4096 + tid * 16);
    {
      const ushort* vr = Vbase + (long)vkv * 512 + vdb;
      short8 va = *(const short8*)vr;
      short8 vb = *(const short8*)(vr + 8);
#pragma unroll
      for (int j = 0; j < 8; j++) {
        int d1 = vdb + j, d2 = vdb + 8 + j;
        *(ushort*)((char*)VTs[0] + d1*128 + ((vkv*2) ^ ((d1 & 7) << 4))) = (ushort)va[j];
        *(ushort*)((char*)VTs[0] + d2*128 + ((vkv*2) ^ ((d2 & 7) << 4))) = (ushort)vb[j];
      }
    }
    __syncthreads();

    int cur = 0;
#pragma unroll 1
    for (int t = 0; t < ntiles; t++) {
      const bool hasn = (t + 1 < ntiles);
      short8 vaN, vbN;
      if (hasn) {
        const long n0g = (long)(t + 1) * 64;
        gload16(Kbase + (n0g + krow) * 2048 + kswz, (char*)Ks[cur ^ 1] + tid * 16);
        gload16(Kbase + (n0g + 32 + krow) * 2048 + kswz, (char*)Ks[cur ^ 1] + 4096 + tid * 16);
        const ushort* vr = Vbase + (n0g + vkv) * 512 + vdb;
        vaN = *(const short8*)vr;
        vbN = *(const short8*)(vr + 8);
      }

      f32x4 sa[4];
#pragma unroll
      for (int n = 0; n < 4; n++) sa[n] = (f32x4){0.f, 0.f, 0.f, 0.f};
#pragma unroll
      for (int ks = 0; ks < 2; ks++) {
        const bf16x8 qf = ks ? qf1 : qf0;
#pragma unroll
        for (int n = 0; n < 4; n++) {
          const int row = n*16 + l16;
          bf16x8 kf = *(const bf16x8*)((const char*)Ks[cur] + row*128 + ((ks*64 + lq*16) ^ ((row & 7) << 4)));
          sa[n] = __builtin_amdgcn_mfma_f32_16x16x32_bf16(qf, kf, sa[n], 0, 0, 0);
        }
      }

      const bool diag = (t == qt);
      float rowmax[4] = {-1e30f, -1e30f, -1e30f, -1e30f};
#pragma unroll
      for (int n = 0; n < 4; n++)
#pragma unroll
        for (int r = 0; r < 4; r++) {
          float sv = sa[n][r] * 0.125f;
          if (diag && (n*16 + l16 > w*16 + lq*4 + r)) sv = -1e30f;
          sa[n][r] = sv;
          rowmax[r] = fmaxf(rowmax[r], sv);
        }
#pragma unroll
      for (int r = 0; r < 4; r++)
#pragma unroll
        for (int off = 8; off; off >>= 1) rowmax[r] = fmaxf(rowmax[r], __shfl_xor(rowmax[r], off));

      float psum[4];
#pragma unroll
      for (int r = 0; r < 4; r++) {
        const float mn = fmaxf(m_[r], rowmax[r]);
        const float corr = __expf(m_[r] - mn);
        m_[r] = mn;
        l_[r] *= corr;
#pragma unroll
        for (int dt = 0; dt < 4; dt++) od[dt][r] *= corr;
        psum[r] = 0.f;
      }
#pragma unroll
      for (int n = 0; n < 4; n++)
#pragma unroll
        for (int r = 0; r < 4; r++) {
          const float pv = __expf(sa[n][r] - m_[r]);
          psum[r] += pv;
          const int prow = w*16 + lq*4 + r;
          *(ushort*)((char*)Ps + prow*128 + (((n*16 + l16)*2) ^ ((prow & 7) << 4))) = f2bf(pv);
        }
#pragma unroll
      for (int r = 0; r < 4; r++) {
#pragma unroll
        for (int off = 8; off; off >>= 1) psum[r] += __shfl_xor(psum[r], off);
        l_[r] += psum[r];
      }

#pragma unroll
      for (int ks = 0; ks < 2; ks++) {
        const int prow = w*16 + l16;
        bf16x8 pf = *(const bf16x8*)((const char*)Ps + prow*128 + ((ks*64 + lq*16) ^ ((prow & 7) << 4)));
#pragma unroll
        for (int dt = 0; dt < 4; dt++) {
          const int vrow = dt*16 + l16;
          bf16x8 vf = *(const bf16x8*)((const char*)VTs[cur] + vrow*128 + ((ks*64 + lq*16) ^ ((vrow & 7) << 4)));
          od[dt] = __builtin_amdgcn_mfma_f32_16x16x32_bf16(pf, vf, od[dt], 0, 0, 0);
        }
      }

      if (hasn) {
#pragma unroll
        for (int j = 0; j < 8; j++) {
          int d1 = vdb + j, d2 = vdb + 8 + j;
          *(ushort*)((char*)VTs[cur ^ 1] + d1*128 + ((vkv*2) ^ ((d1 & 7) << 4))) = (ushort)vaN[j];
          *(ushort*)((char*)VTs[cur ^ 1] + d2*128 + ((vkv*2) ^ ((d2 & 7) << 4))) = (ushort)vbN[j];
        }
      }
      __syncthreads();
      cur ^= 1;
    }

#pragma unroll
    for (int r = 0; r < 4; r++) {
      const float inv = 1.f / l_[r];
      ushort* orow = o + (tokbase + q0 + w*16 + lq*4 + r) * 512 + h * 64 + l16;
#pragma unroll
      for (int dt = 0; dt < 4; dt++) orow[dt*16] = f2bf(od[dt][r] * inv);
    }
  }
}

// ---------------------------------------------------------------------------
// One-shot conversion kernel (all weights + qk bias merge).
// ---------------------------------------------------------------------------
DEVI void cvt8(const float* s, ushort* d) {
  float4 u = *(const float4*)s, v = *(const float4*)(s + 4);
  short8 o;
  o[0]=(short)f2bf(u.x); o[1]=(short)f2bf(u.y); o[2]=(short)f2bf(u.z); o[3]=(short)f2bf(u.w);
  o[4]=(short)f2bf(v.x); o[5]=(short)f2bf(v.y); o[6]=(short)f2bf(v.z); o[7]=(short)f2bf(v.w);
  *(short8*)d = o;
}
__global__ __launch_bounds__(256) void cvt_all(
    const float* __restrict__ q_w, const float* __restrict__ k_w,
    const float* __restrict__ ao_w, const float* __restrict__ vout_w,
    const float* __restrict__ up_w, const float* __restrict__ down_w,
    const float* __restrict__ temb, const float* __restrict__ q_b,
    const float* __restrict__ k_b,
    ushort* __restrict__ Bcat, ushort* __restrict__ aowh, ushort* __restrict__ voutwh,
    ushort* __restrict__ upwh, ushort* __restrict__ downwh, ushort* __restrict__ tembh,
    float* __restrict__ qkb)
{
  long u = (long)blockIdx.x * 256 + threadIdx.x;
  if (u < 262144) {
    long e = u * 8;
    int l = (int)(e >> 19);
    long rem = e & 524287;
    bool isk = rem >= 262144;
    long so = rem & 262143;
    cvt8((isk ? k_w : q_w) + (long)l * 262144 + so,
         Bcat + (long)l * 2752512 + 131072 + (isk ? 262144 : 0) + so);
    return;
  }
  u -= 262144;
  if (u < 131072) { cvt8(ao_w + u*8, aowh + u*8); return; }
  u -= 131072;
  if (u < 32768)  { cvt8(vout_w + u*8, voutwh + u*8); return; }
  u -= 32768;
  if (u < 524288) { cvt8(up_w + u*8, upwh + u*8); return; }
  u -= 524288;
  if (u < 524288) { cvt8(down_w + u*8, downwh + u*8); return; }
  u -= 524288;
  if (u < 2048000){ cvt8(temb + u*8, tembh + u*8); return; }
  u -= 2048000;
  {
    long i8 = u * 8;
    int l = (int)(i8 >> 10), c = (int)(i8 & 1023);
    const float* src = (c < 512) ? (q_b + l*512 + c) : (k_b + l*512 + c - 512);
    float* dst = qkb + i8;
    *(float4*)dst = *(const float4*)src;
    *(float4*)(dst + 4) = *(const float4*)(src + 4);
  }
}

// basis_A [32][512][128] f32 -> Bcat[l] rows 1280.. as [32][128][512] bf16
__global__ __launch_bounds__(256) void transpose_basisA(
    const float* __restrict__ src, ushort* __restrict__ Bcat)
{
  __shared__ ushort tile[64][132];
  const int n = blockIdx.x;
  const int d0 = blockIdx.y * 64;
  const int l = blockIdx.z;
  ushort* dst = Bcat + (long)l * 2752512 + 655360;
  const int tid = threadIdx.x;
#pragma unroll
  for (int it = 0; it < 8; it++) {
    int d = it * 8 + (tid >> 5);
    int rr = (tid & 31) * 4;
    float4 v = *(const float4*)(src + ((long)n * 512 + d0 + d) * 128 + rr);
    tile[d][rr + 0] = f2bf(v.x);
    tile[d][rr + 1] = f2bf(v.y);
    tile[d][rr + 2] = f2bf(v.z);
    tile[d][rr + 3] = f2bf(v.w);
  }
  __syncthreads();
#pragma unroll
  for (int it = 0; it < 4; it++) {
    int rr = it * 32 + (tid >> 3);
    int dof = (tid & 7) * 8;
    short8 s;
#pragma unroll
    for (int j = 0; j < 8; j++) s[j] = (short)tile[dof + j][rr];
    *(short8*)(dst + ((long)n * 128 + rr) * 512 + d0 + dof) = s;
  }
}

// embed + LN1(layer0)
__global__ __launch_bounds__(256) void embed_ln(
    const int* __restrict__ ids, const float* __restrict__ tok,
    const float* __restrict__ pos, const float* __restrict__ gam,
    const float* __restrict__ bet, float* __restrict__ x, ushort* __restrict__ outh)
{
  int row = blockIdx.x * 4 + (threadIdx.x >> 6);
  int lane = threadIdx.x & 63;
  int id = ids[row], sp = row & 1023;
  const float* tp = tok + (long)id * 512;
  const float* pp = pos + (long)sp * 512;
  float4 v0 = *(const float4*)(tp + lane*4);
  float4 p0 = *(const float4*)(pp + lane*4);
  float4 v1 = *(const float4*)(tp + 256 + lane*4);
  float4 p1 = *(const float4*)(pp + 256 + lane*4);
  v0.x+=p0.x; v0.y+=p0.y; v0.z+=p0.z; v0.w+=p0.w;
  v1.x+=p1.x; v1.y+=p1.y; v1.z+=p1.z; v1.w+=p1.w;
  *(float4*)(x + (long)row*512 + lane*4) = v0;
  *(float4*)(x + (long)row*512 + 256 + lane*4) = v1;
  float s = v0.x+v0.y+v0.z+v0.w + v1.x+v1.y+v1.z+v1.w;
#pragma unroll
  for (int o = 32; o; o >>= 1) s += __shfl_xor(s, o);
  float mean = s * (1.f/512.f);
  float d0=v0.x-mean, d1=v0.y-mean, d2=v0.z-mean, d3=v0.w-mean;
  float e0=v1.x-mean, e1=v1.y-mean, e2=v1.z-mean, e3=v1.w-mean;
  float qv = d0*d0+d1*d1+d2*d2+d3*d3 + e0*e0+e1*e1+e2*e2+e3*e3;
#pragma unroll
  for (int o = 32; o; o >>= 1) qv += __shfl_xor(qv, o);
  float inv = rsqrtf(qv * (1.f/512.f) + 1e-5f);
  float4 g0 = *(const float4*)(gam + lane*4);
  float4 g1 = *(const float4*)(gam + 256 + lane*4);
  float4 b0 = *(const float4*)(bet + lane*4);
  float4 b1 = *(const float4*)(bet + 256 + lane*4);
  short4v o0, o1;
  o0[0]=(short)f2bf(d0*inv*g0.x + b0.x); o0[1]=(short)f2bf(d1*inv*g0.y + b0.y);
  o0[2]=(short)f2bf(d2*inv*g0.z + b0.z); o0[3]=(short)f2bf(d3*inv*g0.w + b0.w);
  o1[0]=(short)f2bf(e0*inv*g1.x + b1.x); o1[1]=(short)f2bf(e1*inv*g1.y + b1.y);
  o1[2]=(short)f2bf(e2*inv*g1.z + b1.z); o1[3]=(short)f2bf(e3*inv*g1.w + b1.w);
  *(short4v*)(outh + (long)row*512 + lane*4) = o0;
  *(short4v*)(outh + (long)row*512 + 256 + lane*4) = o1;
}

__global__ __launch_bounds__(256) void ln_kernel(
    const float* __restrict__ in, ushort* __restrict__ outh,
    const float* __restrict__ gam, const float* __restrict__ bet)
{
  int row = blockIdx.x * 4 + (threadIdx.x >> 6);
  int lane = threadIdx.x & 63;
  const float* p = in + (long)row * 512;
  float4 v0 = *(const float4*)(p + lane * 4);
  float4 v1 = *(const float4*)(p + 256 + lane * 4);
  float s = v0.x+v0.y+v0.z+v0.w + v1.x+v1.y+v1.z+v1.w;
#pragma unroll
  for (int o = 32; o; o >>= 1) s += __shfl_xor(s, o);
  float mean = s * (1.f/512.f);
  float d0=v0.x-mean, d1=v0.y-mean, d2=v0.z-mean, d3=v0.w-mean;
  float e0=v1.x-mean, e1=v1.y-mean, e2=v1.z-mean, e3=v1.w-mean;
  float qv = d0*d0+d1*d1+d2*d2+d3*d3 + e0*e0+e1*e1+e2*e2+e3*e3;
#pragma unroll
  for (int o = 32; o; o >>= 1) qv += __shfl_xor(qv, o);
  float inv = rsqrtf(qv * (1.f/512.f) + 1e-5f);
  float4 g0 = *(const float4*)(gam + lane*4);
  float4 g1 = *(const float4*)(gam + 256 + lane*4);
  float4 b0 = *(const float4*)(bet + lane*4);
  float4 b1 = *(const float4*)(bet + 256 + lane*4);
  short4v o0, o1;
  o0[0]=(short)f2bf(d0*inv*g0.x + b0.x); o0[1]=(short)f2bf(d1*inv*g0.y + b0.y);
  o0[2]=(short)f2bf(d2*inv*g0.z + b0.z); o0[3]=(short)f2bf(d3*inv*g0.w + b0.w);
  o1[0]=(short)f2bf(e0*inv*g1.x + b1.x); o1[1]=(short)f2bf(e1*inv*g1.y + b1.y);
  o1[2]=(short)f2bf(e2*inv*g1.z + b1.z); o1[3]=(short)f2bf(e3*inv*g1.w + b1.w);
  *(short4v*)(outh + (long)row*512 + lane*4) = o0;
  *(short4v*)(outh + (long)row*512 + 256 + lane*4) = o1;
}

__global__ __launch_bounds__(64) void precompute_kernel(
    const float* __restrict__ recipe, const float* __restrict__ basis_emb,
    const float* __restrict__ ctx_pat, float* __restrict__ rec_sm,
    ushort* __restrict__ Bcat, float* __restrict__ gate)
{
  int ln = blockIdx.x;
  int l = ln >> 8, n = ln & 255;
  int lane = threadIdx.x;
  const float* r = recipe + (long)ln * 32;
  float rv[32];
  float m = -1e30f;
#pragma unroll
  for (int j = 0; j < 32; j++) { rv[j] = r[j]; m = fmaxf(m, rv[j]); }
  float sum = 0.f;
#pragma unroll
  for (int j = 0; j < 32; j++) { rv[j] = expf(rv[j] - m); sum += rv[j]; }
  float inv = 1.f / sum;
#pragma unroll
  for (int j = 0; j < 32; j++) rv[j] *= inv;
  if (lane < 32) rec_sm[(long)ln * 32 + lane] = rv[lane];
  ushort* dst = Bcat + (long)l * 2752512 + (long)n * 512;
#pragma unroll
  for (int cc = 0; cc < 8; cc++) {
    int c = lane + cc * 64;
    float acc = 0.f;
#pragma unroll
    for (int j = 0; j < 32; j++) acc += rv[j] * basis_emb[j * 512 + c];
    dst[c] = f2bf(acc);
  }
  if (lane == 0) {
    float sh = 0.f;
#pragma unroll
    for (int h = 0; h < 8; h++) sh += ctx_pat[(long)ln * 8 + h];
    gate[ln] = 1.f / (1.f + expf(-sh * (1.f/1024.f)));
  }
}

// fused: top-8 + weight softmax + token_recipe + v_sem (vectorized XA read)
__global__ __launch_bounds__(256) void topkvsem_kernel(
    const float* __restrict__ fin, const float* __restrict__ rec_sm_l,
    const ushort* __restrict__ XA, ushort* __restrict__ out)
{
  __shared__ float trs[4][32];
  int wv = threadIdx.x >> 6, lane = threadIdx.x & 63;
  int t = blockIdx.x * 4 + wv;
  const float* f = fin + (long)t * 256;
  float v0 = f[lane], v1 = f[lane+64], v2 = f[lane+128], v3 = f[lane+192];
  int i0 = lane, i1 = lane+64, i2 = lane+128, i3 = lane+192;
  float topv[8]; int topi[8];
#pragma unroll
  for (int it = 0; it < 8; it++) {
    float bm = v0; int bi = i0;
    if (v1 > bm || (v1 == bm && i1 < bi)) { bm = v1; bi = i1; }
    if (v2 > bm || (v2 == bm && i2 < bi)) { bm = v2; bi = i2; }
    if (v3 > bm || (v3 == bm && i3 < bi)) { bm = v3; bi = i3; }
#pragma unroll
    for (int o = 32; o; o >>= 1) {
      float om = __shfl_xor(bm, o);
      int oi = __shfl_xor(bi, o);
      if (om > bm || (om == bm && oi < bi)) { bm = om; bi = oi; }
    }
    topv[it] = bm; topi[it] = bi;
    if (i0 == bi) v0 = -1e30f;
    if (i1 == bi) v1 = -1e30f;
    if (i2 == bi) v2 = -1e30f;
    if (i3 == bi) v3 = -1e30f;
  }
  float w[8], wsum = 0.f;
#pragma unroll
  for (int k = 0; k < 8; k++) { w[k] = expf(topv[k] - topv[0]); wsum += w[k]; }
  float winv = 1.f / wsum;
  if (lane < 32) {
    float acc = 0.f;
#pragma unroll
    for (int k = 0; k < 8; k++)
      acc += (w[k] * winv) * rec_sm_l[(long)topi[k] * 32 + lane];
    trs[wv][lane] = acc;
  }
  __syncthreads();
  const ushort* xa = XA + (long)t * 4096;
  float a0 = 0.f, a1 = 0.f;
#pragma unroll
  for (int n = 0; n < 32; n++) {
    float wn = trs[wv][n];
    uint u = *(const uint*)&xa[n*128 + 2*lane];
    a0 += wn * bf2f((ushort)(u & 0xffffu));
    a1 += wn * bf2f((ushort)(u >> 16));
  }
  uint o = (uint)f2bf(a0) | ((uint)f2bf(a1) << 16);
  *(uint*)&out[(long)t * 128 + 2*lane] = o;
}

// ---------------------------------------------------------------------------
// host
// ---------------------------------------------------------------------------
extern "C" void kernel_launch(void* const* d_in, const int* in_sizes, int n_in,
                              void* d_out, int out_size, void* d_ws, size_t ws_size,
                              hipStream_t stream) {
  (void)in_sizes; (void)n_in; (void)out_size; (void)ws_size;
  const int*   ids       = (const int*)  d_in[0];
  const float* token_emb = (const float*)d_in[1];
  const float* pos_emb   = (const float*)d_in[2];
  const float* basis_A   = (const float*)d_in[3];
  const float* basis_emb = (const float*)d_in[4];
  const float* q_w  = (const float*)d_in[5];
  const float* q_b  = (const float*)d_in[6];
  const float* k_w  = (const float*)d_in[7];
  const float* k_b  = (const float*)d_in[8];
  const float* ao_w = (const float*)d_in[9];
  const float* ao_b = (const float*)d_in[10];
  const float* recipe  = (const float*)d_in[11];
  const float* ctx_pat = (const float*)d_in[12];
  const float* vout_w  = (const float*)d_in[13];
  const float* vout_b  = (const float*)d_in[14];
  const float* up_w    = (const float*)d_in[15];
  const float* up_b    = (const float*)d_in[16];
  const float* down_w  = (const float*)d_in[17];
  const float* down_b  = (const float*)d_in[18];
  const float* ln1_s = (const float*)d_in[19];
  const float* ln1_b = (const float*)d_in[20];
  const float* ln2_s = (const float*)d_in[21];
  const float* ln2_b = (const float*)d_in[22];
  const float* lnf_s = (const float*)d_in[23];
  const float* lnf_b = (const float*)d_in[24];
  float* out = (float*)d_out;

  float* ws    = (float*)d_ws;
  float* x     = ws;                 // [4096,512] f32
  float* finb  = x + 2097152;        // [4096,256] f32
  float* recsm = finb + 1048576;     // [4,256,32] f32
  float* gate  = recsm + 32768;      // [4,256] f32
  float* qkb   = gate + 1024;        // [4,1024] f32
  ushort* u = (ushort*)(qkb + 4096);
  ushort* nrmh    = u; u += 2097152;    // [4096,512]
  ushort* vsemh   = u; u += 524288;     // [4096,128]
  ushort* Bcat    = u; u += 11010048;   // [4][5376,512]
  ushort* aowh    = u; u += 1048576;    // [4,512,512]
  ushort* voutwh  = u; u += 262144;     // [4,512,128]
  ushort* upwh    = u; u += 4194304;    // [4,2048,512]
  ushort* downwh  = u; u += 4194304;    // [4,512,2048]
  ushort* tembh   = u; u += 16384000;   // [32000,512]

  ushort* XAb = (ushort*)out;              // [4096,4096] @ 0
  ushort* HF  = (ushort*)out;              // [4096,2048] @ 0
  ushort* qkh = (ushort*)out + 16777216;   // [4096,1024]
  ushort* vvh = (ushort*)out + 20971520;   // [4096,512]
  ushort* aoh = (ushort*)out + 23068672;   // [4096,512]

  cvt_all<<<13762, 256, 0, stream>>>(q_w, k_w, ao_w, vout_w, up_w, down_w,
      token_emb, q_b, k_b, Bcat, aowh, voutwh, upwh, downwh, tembh, qkb);
  transpose_basisA<<<dim3(32, 8, 4), 256, 0, stream>>>(basis_A, Bcat);
  precompute_kernel<<<1024, 64, 0, stream>>>(recipe, basis_emb, ctx_pat, recsm, Bcat, gate);
  embed_ln<<<1024, 256, 0, stream>>>(ids, token_emb, pos_emb, ln1_s, ln1_b, x, nrmh);

  for (int l = 0; l < 4; l++) {
    if (l) ln_kernel<<<1024, 256, 0, stream>>>(x, nrmh, ln1_s + l*512, ln1_b + l*512);
    megag1<<<dim3(42, 32), 256, 0, stream>>>(nrmh, Bcat + (long)l*2752512,
        finb, qkh, XAb, gate + l*256, qkb + l*1024);
    topkvsem_kernel<<<1024, 256, 0, stream>>>(finb, recsm + (long)l*8192, XAb, vsemh);
    // Vv: m-stripe 32
    gemmT<32,1><<<dim3(4, 128), 256, 0, stream>>>(vsemh, voutwh + (long)l*65536, vvh,
        vout_b + l*512, 128, 128, 128, 512, 1.f, 32);
    flash_kernel<<<dim3(8, 32), 256, 0, stream>>>(qkh, vvh, aoh);
    // ao proj: m-stripe 32, scalar residual epilogue
    gemmT<32,3><<<dim3(4, 128), 256, 0, stream>>>(aoh, aowh + (long)l*262144, x,
        ao_b + l*512, 512, 512, 512, 512, 1.f, 32);
    ln_kernel<<<1024, 256, 0, stream>>>(x, nrmh, ln2_s + l*512, ln2_b + l*512);
    // up: BM=128 (32 MFMA/barrier-pair, 512 wg = 2 blocks/CU), m-stripe 8
    gemmT<128,2><<<dim3(16, 32), 256, 0, stream>>>(nrmh, upwh + (long)l*1048576, (void*)HF,
        up_b + l*2048, 512, 512, 512, 2048, 1.f, 8);
    // down: m-stripe 32, scalar residual epilogue
    gemmT<32,3><<<dim3(4, 128), 256, 0, stream>>>(HF, downwh + (long)l*1048576, x,
        down_b + l*512, 2048, 2048, 2048, 512, 1.f, 32);
  }

  ln_kernel<<<1024, 256, 0, stream>>>(x, nrmh, lnf_s, lnf_b);
  // logits: n-band of 25, quarter-tile coalesced NT epilogue, Cs aliased (32KB LDS)
  gemmT<128,4><<<dim3(250, 32), 256, 0, stream>>>(nrmh, tembh, out, nullptr,
      512, 512, 512, 32000, 1.f, -25);
}

// Round 13
// 1042.136 us; speedup vs baseline: 1.0127x; 1.0127x over previous
//
#include <hip/hip_runtime.h>
#include <hip/hip_bf16.h>
#include <math.h>

typedef __attribute__((ext_vector_type(8))) short short8;
typedef __attribute__((ext_vector_type(4))) short short4v;
typedef __attribute__((ext_vector_type(8))) __bf16 bf16x8;
typedef __attribute__((ext_vector_type(4))) float f32x4;
typedef unsigned short ushort;
typedef unsigned int uint;

#define DEVI static __device__ __forceinline__

DEVI ushort f2bf(float f) {
  union { float f; unsigned u; } v; v.f = f;
  unsigned r = v.u + 0x7fffu + ((v.u >> 16) & 1u);
  return (ushort)(r >> 16);
}
DEVI float bf2f(ushort h) {
  union { unsigned u; float f; } v; v.u = (unsigned)h << 16; return v.f;
}
DEVI void gload16(const void* g, void* l) {
  __builtin_amdgcn_global_load_lds((const __attribute__((address_space(1))) void*)g,
                                   (__attribute__((address_space(3))) void*)l, 16, 0, 0);
}

// Block-order mapping: XCD swizzle, then row-major / m-stripe / n-band.
DEVI void map_block(int gx, int gy, int BM, int bmode, int& n0, int& m0) {
  const int nwg = gx * gy;
  const int orig = blockIdx.y * gx + blockIdx.x;
  const int qq = nwg >> 3, rr = nwg & 7;
  const int xcd = orig & 7, sidx = orig >> 3;
  const int wg = (xcd < rr ? xcd * (qq + 1) : rr * (qq + 1) + (xcd - rr) * qq) + sidx;
  if (bmode == 0) {
    n0 = (wg % gx) * 128; m0 = (wg / gx) * BM;
  } else if (bmode > 0) {
    const int mh = bmode, bs = gx * mh;
    const int band = wg / bs, wi = wg - band * bs;
    n0 = (wi / mh) * 128;
    m0 = (band * mh + wi % mh) * BM;
  } else {
    const int bn = -bmode, gm = gy, bs = bn * gm;
    const int band = wg / bs, wi = wg - band * bs;
    m0 = (wi / bn) * BM;
    n0 = (band * bn + wi % bn) * 128;
  }
}

// ---------------------------------------------------------------------------
// BMx128 bf16 MFMA GEMM, BK=64. A [M,K] bf16, B [N,K] bf16 (B^T).
// EPI: 1=bf16 store, 2=GELU->bf16, 3=f32 residual add (scalar, sector-aligned),
//      4=f32 NT store (quarter-tile LDS transpose; Cs aliased onto As).
// ---------------------------------------------------------------------------
template<int BM, int EPI>
__global__ __launch_bounds__(256) void gemmT(
    const ushort* __restrict__ A, const ushort* __restrict__ B,
    void* __restrict__ Cv, const float* __restrict__ bias,
    int K, int lda, int ldb, int ldc, float scale, int bmode)
{
  constexpr int BK = 64;
  constexpr int MF = (BM + 31) / 32;
  constexpr int MH = BM / 2;
  constexpr int ACH = BM * BK / 2048;
  constexpr int BCH = 128 * BK / 2048;
  __shared__ ushort As[BM * BK];
  __shared__ ushort Bs[128 * BK];

  int n0, m0;
  map_block(gridDim.x, gridDim.y, BM, bmode, n0, m0);

  const int tid = threadIdx.x;
  const int lane = tid & 63, wv = tid >> 6;
  const int wm = wv >> 1, wn = wv & 1;
  const int l16 = lane & 15, lq = lane >> 4;

  f32x4 acc[MF][4];
#pragma unroll
  for (int i = 0; i < MF; i++)
#pragma unroll
    for (int j = 0; j < 4; j++) acc[i][j] = (f32x4){0.f, 0.f, 0.f, 0.f};

  const char* apS[ACH]; const char* bpS[BCH];
#pragma unroll
  for (int s = 0; s < ACH; s++) {
    int c = tid + 256 * s;
    apS[s] = (const char*)(A + (long)(m0 + (c >> 3)) * lda) + ((c & 7) << 4);
  }
#pragma unroll
  for (int s = 0; s < BCH; s++) {
    int c = tid + 256 * s;
    bpS[s] = (const char*)(B + (long)(n0 + (c >> 3)) * ldb) + ((c & 7) << 4);
  }

  for (int k0 = 0; k0 < K; k0 += BK) {
    const long kb = (long)k0 * 2;
#pragma unroll
    for (int s = 0; s < ACH; s++) gload16(apS[s] + kb, (char*)As + (tid + 256*s) * 16);
#pragma unroll
    for (int s = 0; s < BCH; s++) gload16(bpS[s] + kb, (char*)Bs + (tid + 256*s) * 16);
    __syncthreads();
#pragma unroll
    for (int ks = 0; ks < 2; ks++) {
      bf16x8 af[MF], bfr[4];
#pragma unroll
      for (int i = 0; i < MF; i++)
        af[i] = __builtin_bit_cast(bf16x8, *(const short8*)&As[(wm*MH + i*16 + l16)*BK + ks*32 + lq*8]);
#pragma unroll
      for (int j = 0; j < 4; j++)
        bfr[j] = __builtin_bit_cast(bf16x8, *(const short8*)&Bs[(wn*64 + j*16 + l16)*BK + ks*32 + lq*8]);
#pragma unroll
      for (int i = 0; i < MF; i++)
#pragma unroll
        for (int j = 0; j < 4; j++)
          acc[i][j] = __builtin_amdgcn_mfma_f32_16x16x32_bf16(af[i], bfr[j], acc[i][j], 0, 0, 0);
    }
    __syncthreads();
  }

  float* Cf = (float*)Cv;
  ushort* Ch = (ushort*)Cv;

  if (EPI == 4) {
    // quarter-tile (16 rows) LDS transpose; NT f32x4 stores, 512B/row contiguous.
    // Cs aliased onto As (dead after final barrier): 16*132*4 = 8448 B <= As size.
    float* Cs = (float*)As;
    const int er = tid >> 5, ec = (tid & 31) << 2;
#pragma unroll
    for (int half = 0; half < 2; half++)
#pragma unroll
      for (int i = 0; i < MF; i++) {
        __syncthreads();
        if (wm == half) {
#pragma unroll
          for (int j = 0; j < 4; j++) {
            const int col = wn*64 + j*16 + l16;
            const float cb = bias ? bias[n0 + col] : 0.f;
#pragma unroll
            for (int t = 0; t < 4; t++)
              Cs[(lq*4 + t)*132 + col] = acc[i][j][t] * scale + cb;
          }
        }
        __syncthreads();
#pragma unroll
        for (int ps = 0; ps < 2; ps++) {
          const int row = ps*8 + er;
          f32x4 v = *(const f32x4*)&Cs[row*132 + ec];
          __builtin_nontemporal_store(v,
              (f32x4*)(Cf + (long)(m0 + half*MH + i*16 + row) * ldc + n0 + ec));
        }
      }
  } else {
#pragma unroll
    for (int i = 0; i < MF; i++) {
      const int row0 = m0 + wm*MH + i*16 + lq*4;
#pragma unroll
      for (int j = 0; j < 4; j++) {
        const int col = n0 + wn*64 + j*16 + l16;
        const float cb = bias ? bias[col] : 0.f;
#pragma unroll
        for (int t = 0; t < 4; t++) {
          float val = acc[i][j][t] * scale + cb;
          const long idx = (long)(row0 + t) * ldc + col;
          if (EPI == 1)      Ch[idx] = f2bf(val);
          else if (EPI == 2) { val = 0.5f * val * (1.f + erff(val * 0.70710678118654752f)); Ch[idx] = f2bf(val); }
          else               Cf[idx] += val;
        }
      }
    }
  }
}

// ---------------------------------------------------------------------------
// Mega GEMM (BK=64): A=nrm [4096,512], B=Bcat[l] [5376,512]. Grid (42,32).
// ---------------------------------------------------------------------------
__global__ __launch_bounds__(256) void megag1(
    const ushort* __restrict__ A, const ushort* __restrict__ B,
    float* __restrict__ finb, ushort* __restrict__ qkh, ushort* __restrict__ XAb,
    const float* __restrict__ gate, const float* __restrict__ qkbias)
{
  constexpr int BK = 64;
  __shared__ ushort As[128 * BK];
  __shared__ ushort Bs[128 * BK];
  int n0, m0;
  map_block(gridDim.x, gridDim.y, 128, 8, n0, m0);

  const int tid = threadIdx.x;
  const int lane = tid & 63, wv = tid >> 6;
  const int wm = wv >> 1, wn = wv & 1;
  const int l16 = lane & 15, lq = lane >> 4;

  f32x4 acc[4][4];
#pragma unroll
  for (int i = 0; i < 4; i++)
#pragma unroll
    for (int j = 0; j < 4; j++) acc[i][j] = (f32x4){0.f, 0.f, 0.f, 0.f};

  const char* apS[4]; const char* bpS[4];
#pragma unroll
  for (int s = 0; s < 4; s++) {
    int c = tid + 256 * s;
    apS[s] = (const char*)(A + (long)(m0 + (c >> 3)) * 512) + ((c & 7) << 4);
    bpS[s] = (const char*)(B + (long)(n0 + (c >> 3)) * 512) + ((c & 7) << 4);
  }

  for (int k0 = 0; k0 < 512; k0 += BK) {
    const long kb = (long)k0 * 2;
#pragma unroll
    for (int s = 0; s < 4; s++) {
      gload16(apS[s] + kb, (char*)As + (tid + 256*s) * 16);
      gload16(bpS[s] + kb, (char*)Bs + (tid + 256*s) * 16);
    }
    __syncthreads();
#pragma unroll
    for (int ks = 0; ks < 2; ks++) {
      bf16x8 af[4], bfr[4];
#pragma unroll
      for (int i = 0; i < 4; i++) {
        af[i]  = __builtin_bit_cast(bf16x8, *(const short8*)&As[(wm*64 + i*16 + l16)*BK + ks*32 + lq*8]);
        bfr[i] = __builtin_bit_cast(bf16x8, *(const short8*)&Bs[(wn*64 + i*16 + l16)*BK + ks*32 + lq*8]);
      }
#pragma unroll
      for (int i = 0; i < 4; i++)
#pragma unroll
        for (int j = 0; j < 4; j++)
          acc[i][j] = __builtin_amdgcn_mfma_f32_16x16x32_bf16(af[i], bfr[j], acc[i][j], 0, 0, 0);
    }
    __syncthreads();
  }

#pragma unroll
  for (int i = 0; i < 4; i++) {
    const int row0 = m0 + wm*64 + i*16 + lq*4;
#pragma unroll
    for (int j = 0; j < 4; j++) {
      const int col = n0 + wn*64 + j*16 + l16;
      if (col < 256) {
        const float g = gate[col];
#pragma unroll
        for (int t = 0; t < 4; t++) finb[(long)(row0 + t) * 256 + col] = acc[i][j][t] * g;
      } else if (col < 1280) {
        const int c = col - 256;
        const float bb = qkbias[c];
#pragma unroll
        for (int t = 0; t < 4; t++) qkh[(long)(row0 + t) * 1024 + c] = f2bf(acc[i][j][t] + bb);
      } else {
        const int c = col - 1280;
#pragma unroll
        for (int t = 0; t < 4; t++) XAb[(long)(row0 + t) * 4096 + c] = f2bf(acc[i][j][t]);
      }
    }
  }
}

// ---------------------------------------------------------------------------
// Fused causal flash attention, balanced q-tile pairs {p, 15-p} per block.
// Grid (8, 32). Double-buffered K/V staging.
// ---------------------------------------------------------------------------
__global__ __launch_bounds__(256) void flash_kernel(
    const ushort* __restrict__ qk, const ushort* __restrict__ v,
    ushort* __restrict__ o)
{
  __shared__ ushort Ks[2][4096];
  __shared__ ushort VTs[2][4096];
  __shared__ ushort Ps[4096];
  const int p = blockIdx.x, bh = blockIdx.y;
  const int b = bh >> 3, h = bh & 7;
  const int tid = threadIdx.x, lane = tid & 63, w = tid >> 6;
  const int l16 = lane & 15, lq = lane >> 4;
  const long tokbase = (long)b * 1024;
  const ushort* Qbase = qk + tokbase * 1024 + h * 64;
  const char*   Kbase = (const char*)(qk + tokbase * 1024 + 512 + h * 64);
  const ushort* Vbase = v + tokbase * 512 + h * 64;

  const int krow = tid >> 3, kcb = (tid & 7) << 4;
  const int vkv  = tid >> 2, vdb = (tid & 3) << 4;
  const int kswz = kcb ^ ((krow & 7) << 4);

#pragma unroll 1
  for (int half = 0; half < 2; half++) {
    const int qt = half ? (15 - p) : p;
    const int q0 = qt * 64;
    const int ntiles = qt + 1;

    const ushort* qrow = Qbase + (long)(q0 + w*16 + l16) * 1024;
    const bf16x8 qf0 = *(const bf16x8*)(qrow + lq*8);
    const bf16x8 qf1 = *(const bf16x8*)(qrow + 32 + lq*8);

    float m_[4] = {-1e30f, -1e30f, -1e30f, -1e30f};
    float l_[4] = {0.f, 0.f, 0.f, 0.f};
    f32x4 od[4];
#pragma unroll
    for (int dt = 0; dt < 4; dt++) od[dt] = (f32x4){0.f, 0.f, 0.f, 0.f};

    gload16(Kbase + (long)krow * 2048 + kswz, (char*)Ks[0] + tid * 16);
    gload16(Kbase + (long)(32 + krow) * 2048 + kswz, (char*)Ks[0] + 4096 + tid * 16);
    {
      const ushort* vr = Vbase + (long)vkv * 512 + vdb;
      short8 va = *(const short8*)vr;
      short8 vb = *(const short8*)(vr + 8);
#pragma unroll
      for (int j = 0; j < 8; j++) {
        int d1 = vdb + j, d2 = vdb + 8 + j;
        *(ushort*)((char*)VTs[0] + d1*128 + ((vkv*2) ^ ((d1 & 7) << 4))) = (ushort)va[j];
        *(ushort*)((char*)VTs[0] + d2*128 + ((vkv*2) ^ ((d2 & 7) << 4))) = (ushort)vb[j];
      }
    }
    __syncthreads();

    int cur = 0;
#pragma unroll 1
    for (int t = 0; t < ntiles; t++) {
      const bool hasn = (t + 1 < ntiles);
      short8 vaN, vbN;
      if (hasn) {
        const long n0g = (long)(t + 1) * 64;
        gload16(Kbase + (n0g + krow) * 2048 + kswz, (char*)Ks[cur ^ 1] + tid * 16);
        gload16(Kbase + (n0g + 32 + krow) * 2048 + kswz, (char*)Ks[cur ^ 1] + 4096 + tid * 16);
        const ushort* vr = Vbase + (n0g + vkv) * 512 + vdb;
        vaN = *(const short8*)vr;
        vbN = *(const short8*)(vr + 8);
      }

      f32x4 sa[4];
#pragma unroll
      for (int n = 0; n < 4; n++) sa[n] = (f32x4){0.f, 0.f, 0.f, 0.f};
#pragma unroll
      for (int ks = 0; ks < 2; ks++) {
        const bf16x8 qf = ks ? qf1 : qf0;
#pragma unroll
        for (int n = 0; n < 4; n++) {
          const int row = n*16 + l16;
          bf16x8 kf = *(const bf16x8*)((const char*)Ks[cur] + row*128 + ((ks*64 + lq*16) ^ ((row & 7) << 4)));
          sa[n] = __builtin_amdgcn_mfma_f32_16x16x32_bf16(qf, kf, sa[n], 0, 0, 0);
        }
      }

      const bool diag = (t == qt);
      float rowmax[4] = {-1e30f, -1e30f, -1e30f, -1e30f};
#pragma unroll
      for (int n = 0; n < 4; n++)
#pragma unroll
        for (int r = 0; r < 4; r++) {
          float sv = sa[n][r] * 0.125f;
          if (diag && (n*16 + l16 > w*16 + lq*4 + r)) sv = -1e30f;
          sa[n][r] = sv;
          rowmax[r] = fmaxf(rowmax[r], sv);
        }
#pragma unroll
      for (int r = 0; r < 4; r++)
#pragma unroll
        for (int off = 8; off; off >>= 1) rowmax[r] = fmaxf(rowmax[r], __shfl_xor(rowmax[r], off));

      float psum[4];
#pragma unroll
      for (int r = 0; r < 4; r++) {
        const float mn = fmaxf(m_[r], rowmax[r]);
        const float corr = __expf(m_[r] - mn);
        m_[r] = mn;
        l_[r] *= corr;
#pragma unroll
        for (int dt = 0; dt < 4; dt++) od[dt][r] *= corr;
        psum[r] = 0.f;
      }
#pragma unroll
      for (int n = 0; n < 4; n++)
#pragma unroll
        for (int r = 0; r < 4; r++) {
          const float pv = __expf(sa[n][r] - m_[r]);
          psum[r] += pv;
          const int prow = w*16 + lq*4 + r;
          *(ushort*)((char*)Ps + prow*128 + (((n*16 + l16)*2) ^ ((prow & 7) << 4))) = f2bf(pv);
        }
#pragma unroll
      for (int r = 0; r < 4; r++) {
#pragma unroll
        for (int off = 8; off; off >>= 1) psum[r] += __shfl_xor(psum[r], off);
        l_[r] += psum[r];
      }

#pragma unroll
      for (int ks = 0; ks < 2; ks++) {
        const int prow = w*16 + l16;
        bf16x8 pf = *(const bf16x8*)((const char*)Ps + prow*128 + ((ks*64 + lq*16) ^ ((prow & 7) << 4)));
#pragma unroll
        for (int dt = 0; dt < 4; dt++) {
          const int vrow = dt*16 + l16;
          bf16x8 vf = *(const bf16x8*)((const char*)VTs[cur] + vrow*128 + ((ks*64 + lq*16) ^ ((vrow & 7) << 4)));
          od[dt] = __builtin_amdgcn_mfma_f32_16x16x32_bf16(pf, vf, od[dt], 0, 0, 0);
        }
      }

      if (hasn) {
#pragma unroll
        for (int j = 0; j < 8; j++) {
          int d1 = vdb + j, d2 = vdb + 8 + j;
          *(ushort*)((char*)VTs[cur ^ 1] + d1*128 + ((vkv*2) ^ ((d1 & 7) << 4))) = (ushort)vaN[j];
          *(ushort*)((char*)VTs[cur ^ 1] + d2*128 + ((vkv*2) ^ ((d2 & 7) << 4))) = (ushort)vbN[j];
        }
      }
      __syncthreads();
      cur ^= 1;
    }

#pragma unroll
    for (int r = 0; r < 4; r++) {
      const float inv = 1.f / l_[r];
      ushort* orow = o + (tokbase + q0 + w*16 + lq*4 + r) * 512 + h * 64 + l16;
#pragma unroll
      for (int dt = 0; dt < 4; dt++) orow[dt*16] = f2bf(od[dt][r] * inv);
    }
  }
}

// ---------------------------------------------------------------------------
// One-shot conversion kernel (all weights + qk bias merge).
// ---------------------------------------------------------------------------
DEVI void cvt8(const float* s, ushort* d) {
  float4 u = *(const float4*)s, v = *(const float4*)(s + 4);
  short8 o;
  o[0]=(short)f2bf(u.x); o[1]=(short)f2bf(u.y); o[2]=(short)f2bf(u.z); o[3]=(short)f2bf(u.w);
  o[4]=(short)f2bf(v.x); o[5]=(short)f2bf(v.y); o[6]=(short)f2bf(v.z); o[7]=(short)f2bf(v.w);
  *(short8*)d = o;
}
__global__ __launch_bounds__(256) void cvt_all(
    const float* __restrict__ q_w, const float* __restrict__ k_w,
    const float* __restrict__ ao_w, const float* __restrict__ vout_w,
    const float* __restrict__ up_w, const float* __restrict__ down_w,
    const float* __restrict__ temb, const float* __restrict__ q_b,
    const float* __restrict__ k_b,
    ushort* __restrict__ Bcat, ushort* __restrict__ aowh, ushort* __restrict__ voutwh,
    ushort* __restrict__ upwh, ushort* __restrict__ downwh, ushort* __restrict__ tembh,
    float* __restrict__ qkb)
{
  long u = (long)blockIdx.x * 256 + threadIdx.x;
  if (u < 262144) {
    long e = u * 8;
    int l = (int)(e >> 19);
    long rem = e & 524287;
    bool isk = rem >= 262144;
    long so = rem & 262143;
    cvt8((isk ? k_w : q_w) + (long)l * 262144 + so,
         Bcat + (long)l * 2752512 + 131072 + (isk ? 262144 : 0) + so);
    return;
  }
  u -= 262144;
  if (u < 131072) { cvt8(ao_w + u*8, aowh + u*8); return; }
  u -= 131072;
  if (u < 32768)  { cvt8(vout_w + u*8, voutwh + u*8); return; }
  u -= 32768;
  if (u < 524288) { cvt8(up_w + u*8, upwh + u*8); return; }
  u -= 524288;
  if (u < 524288) { cvt8(down_w + u*8, downwh + u*8); return; }
  u -= 524288;
  if (u < 2048000){ cvt8(temb + u*8, tembh + u*8); return; }
  u -= 2048000;
  {
    long i8 = u * 8;
    int l = (int)(i8 >> 10), c = (int)(i8 & 1023);
    const float* src = (c < 512) ? (q_b + l*512 + c) : (k_b + l*512 + c - 512);
    float* dst = qkb + i8;
    *(float4*)dst = *(const float4*)src;
    *(float4*)(dst + 4) = *(const float4*)(src + 4);
  }
}

// basis_A [32][512][128] f32 -> Bcat[l] rows 1280.. as [32][128][512] bf16
__global__ __launch_bounds__(256) void transpose_basisA(
    const float* __restrict__ src, ushort* __restrict__ Bcat)
{
  __shared__ ushort tile[64][132];
  const int n = blockIdx.x;
  const int d0 = blockIdx.y * 64;
  const int l = blockIdx.z;
  ushort* dst = Bcat + (long)l * 2752512 + 655360;
  const int tid = threadIdx.x;
#pragma unroll
  for (int it = 0; it < 8; it++) {
    int d = it * 8 + (tid >> 5);
    int rr = (tid & 31) * 4;
    float4 v = *(const float4*)(src + ((long)n * 512 + d0 + d) * 128 + rr);
    tile[d][rr + 0] = f2bf(v.x);
    tile[d][rr + 1] = f2bf(v.y);
    tile[d][rr + 2] = f2bf(v.z);
    tile[d][rr + 3] = f2bf(v.w);
  }
  __syncthreads();
#pragma unroll
  for (int it = 0; it < 4; it++) {
    int rr = it * 32 + (tid >> 3);
    int dof = (tid & 7) * 8;
    short8 s;
#pragma unroll
    for (int j = 0; j < 8; j++) s[j] = (short)tile[dof + j][rr];
    *(short8*)(dst + ((long)n * 128 + rr) * 512 + d0 + dof) = s;
  }
}

// embed + LN1(layer0)
__global__ __launch_bounds__(256) void embed_ln(
    const int* __restrict__ ids, const float* __restrict__ tok,
    const float* __restrict__ pos, const float* __restrict__ gam,
    const float* __restrict__ bet, float* __restrict__ x, ushort* __restrict__ outh)
{
  int row = blockIdx.x * 4 + (threadIdx.x >> 6);
  int lane = threadIdx.x & 63;
  int id = ids[row], sp = row & 1023;
  const float* tp = tok + (long)id * 512;
  const float* pp = pos + (long)sp * 512;
  float4 v0 = *(const float4*)(tp + lane*4);
  float4 p0 = *(const float4*)(pp + lane*4);
  float4 v1 = *(const float4*)(tp + 256 + lane*4);
  float4 p1 = *(const float4*)(pp + 256 + lane*4);
  v0.x+=p0.x; v0.y+=p0.y; v0.z+=p0.z; v0.w+=p0.w;
  v1.x+=p1.x; v1.y+=p1.y; v1.z+=p1.z; v1.w+=p1.w;
  *(float4*)(x + (long)row*512 + lane*4) = v0;
  *(float4*)(x + (long)row*512 + 256 + lane*4) = v1;
  float s = v0.x+v0.y+v0.z+v0.w + v1.x+v1.y+v1.z+v1.w;
#pragma unroll
  for (int o = 32; o; o >>= 1) s += __shfl_xor(s, o);
  float mean = s * (1.f/512.f);
  float d0=v0.x-mean, d1=v0.y-mean, d2=v0.z-mean, d3=v0.w-mean;
  float e0=v1.x-mean, e1=v1.y-mean, e2=v1.z-mean, e3=v1.w-mean;
  float qv = d0*d0+d1*d1+d2*d2+d3*d3 + e0*e0+e1*e1+e2*e2+e3*e3;
#pragma unroll
  for (int o = 32; o; o >>= 1) qv += __shfl_xor(qv, o);
  float inv = rsqrtf(qv * (1.f/512.f) + 1e-5f);
  float4 g0 = *(const float4*)(gam + lane*4);
  float4 g1 = *(const float4*)(gam + 256 + lane*4);
  float4 b0 = *(const float4*)(bet + lane*4);
  float4 b1 = *(const float4*)(bet + 256 + lane*4);
  short4v o0, o1;
  o0[0]=(short)f2bf(d0*inv*g0.x + b0.x); o0[1]=(short)f2bf(d1*inv*g0.y + b0.y);
  o0[2]=(short)f2bf(d2*inv*g0.z + b0.z); o0[3]=(short)f2bf(d3*inv*g0.w + b0.w);
  o1[0]=(short)f2bf(e0*inv*g1.x + b1.x); o1[1]=(short)f2bf(e1*inv*g1.y + b1.y);
  o1[2]=(short)f2bf(e2*inv*g1.z + b1.z); o1[3]=(short)f2bf(e3*inv*g1.w + b1.w);
  *(short4v*)(outh + (long)row*512 + lane*4) = o0;
  *(short4v*)(outh + (long)row*512 + 256 + lane*4) = o1;
}

__global__ __launch_bounds__(256) void ln_kernel(
    const float* __restrict__ in, ushort* __restrict__ outh,
    const float* __restrict__ gam, const float* __restrict__ bet)
{
  int row = blockIdx.x * 4 + (threadIdx.x >> 6);
  int lane = threadIdx.x & 63;
  const float* p = in + (long)row * 512;
  float4 v0 = *(const float4*)(p + lane * 4);
  float4 v1 = *(const float4*)(p + 256 + lane * 4);
  float s = v0.x+v0.y+v0.z+v0.w + v1.x+v1.y+v1.z+v1.w;
#pragma unroll
  for (int o = 32; o; o >>= 1) s += __shfl_xor(s, o);
  float mean = s * (1.f/512.f);
  float d0=v0.x-mean, d1=v0.y-mean, d2=v0.z-mean, d3=v0.w-mean;
  float e0=v1.x-mean, e1=v1.y-mean, e2=v1.z-mean, e3=v1.w-mean;
  float qv = d0*d0+d1*d1+d2*d2+d3*d3 + e0*e0+e1*e1+e2*e2+e3*e3;
#pragma unroll
  for (int o = 32; o; o >>= 1) qv += __shfl_xor(qv, o);
  float inv = rsqrtf(qv * (1.f/512.f) + 1e-5f);
  float4 g0 = *(const float4*)(gam + lane*4);
  float4 g1 = *(const float4*)(gam + 256 + lane*4);
  float4 b0 = *(const float4*)(bet + lane*4);
  float4 b1 = *(const float4*)(bet + 256 + lane*4);
  short4v o0, o1;
  o0[0]=(short)f2bf(d0*inv*g0.x + b0.x); o0[1]=(short)f2bf(d1*inv*g0.y + b0.y);
  o0[2]=(short)f2bf(d2*inv*g0.z + b0.z); o0[3]=(short)f2bf(d3*inv*g0.w + b0.w);
  o1[0]=(short)f2bf(e0*inv*g1.x + b1.x); o1[1]=(short)f2bf(e1*inv*g1.y + b1.y);
  o1[2]=(short)f2bf(e2*inv*g1.z + b1.z); o1[3]=(short)f2bf(e3*inv*g1.w + b1.w);
  *(short4v*)(outh + (long)row*512 + lane*4) = o0;
  *(short4v*)(outh + (long)row*512 + 256 + lane*4) = o1;
}

__global__ __launch_bounds__(64) void precompute_kernel(
    const float* __restrict__ recipe, const float* __restrict__ basis_emb,
    const float* __restrict__ ctx_pat, float* __restrict__ rec_sm,
    ushort* __restrict__ Bcat, float* __restrict__ gate)
{
  int ln = blockIdx.x;
  int l = ln >> 8, n = ln & 255;
  int lane = threadIdx.x;
  const float* r = recipe + (long)ln * 32;
  float rv[32];
  float m = -1e30f;
#pragma unroll
  for (int j = 0; j < 32; j++) { rv[j] = r[j]; m = fmaxf(m, rv[j]); }
  float sum = 0.f;
#pragma unroll
  for (int j = 0; j < 32; j++) { rv[j] = expf(rv[j] - m); sum += rv[j]; }
  float inv = 1.f / sum;
#pragma unroll
  for (int j = 0; j < 32; j++) rv[j] *= inv;
  if (lane < 32) rec_sm[(long)ln * 32 + lane] = rv[lane];
  ushort* dst = Bcat + (long)l * 2752512 + (long)n * 512;
#pragma unroll
  for (int cc = 0; cc < 8; cc++) {
    int c = lane + cc * 64;
    float acc = 0.f;
#pragma unroll
    for (int j = 0; j < 32; j++) acc += rv[j] * basis_emb[j * 512 + c];
    dst[c] = f2bf(acc);
  }
  if (lane == 0) {
    float sh = 0.f;
#pragma unroll
    for (int h = 0; h < 8; h++) sh += ctx_pat[(long)ln * 8 + h];
    gate[ln] = 1.f / (1.f + expf(-sh * (1.f/1024.f)));
  }
}

// fused: top-8 + weight softmax + token_recipe + v_sem (vectorized XA read)
__global__ __launch_bounds__(256) void topkvsem_kernel(
    const float* __restrict__ fin, const float* __restrict__ rec_sm_l,
    const ushort* __restrict__ XA, ushort* __restrict__ out)
{
  __shared__ float trs[4][32];
  int wv = threadIdx.x >> 6, lane = threadIdx.x & 63;
  int t = blockIdx.x * 4 + wv;
  const float* f = fin + (long)t * 256;
  float v0 = f[lane], v1 = f[lane+64], v2 = f[lane+128], v3 = f[lane+192];
  int i0 = lane, i1 = lane+64, i2 = lane+128, i3 = lane+192;
  float topv[8]; int topi[8];
#pragma unroll
  for (int it = 0; it < 8; it++) {
    float bm = v0; int bi = i0;
    if (v1 > bm || (v1 == bm && i1 < bi)) { bm = v1; bi = i1; }
    if (v2 > bm || (v2 == bm && i2 < bi)) { bm = v2; bi = i2; }
    if (v3 > bm || (v3 == bm && i3 < bi)) { bm = v3; bi = i3; }
#pragma unroll
    for (int o = 32; o; o >>= 1) {
      float om = __shfl_xor(bm, o);
      int oi = __shfl_xor(bi, o);
      if (om > bm || (om == bm && oi < bi)) { bm = om; bi = oi; }
    }
    topv[it] = bm; topi[it] = bi;
    if (i0 == bi) v0 = -1e30f;
    if (i1 == bi) v1 = -1e30f;
    if (i2 == bi) v2 = -1e30f;
    if (i3 == bi) v3 = -1e30f;
  }
  float w[8], wsum = 0.f;
#pragma unroll
  for (int k = 0; k < 8; k++) { w[k] = expf(topv[k] - topv[0]); wsum += w[k]; }
  float winv = 1.f / wsum;
  if (lane < 32) {
    float acc = 0.f;
#pragma unroll
    for (int k = 0; k < 8; k++)
      acc += (w[k] * winv) * rec_sm_l[(long)topi[k] * 32 + lane];
    trs[wv][lane] = acc;
  }
  __syncthreads();
  const ushort* xa = XA + (long)t * 4096;
  float a0 = 0.f, a1 = 0.f;
#pragma unroll
  for (int n = 0; n < 32; n++) {
    float wn = trs[wv][n];
    uint u = *(const uint*)&xa[n*128 + 2*lane];
    a0 += wn * bf2f((ushort)(u & 0xffffu));
    a1 += wn * bf2f((ushort)(u >> 16));
  }
  uint o = (uint)f2bf(a0) | ((uint)f2bf(a1) << 16);
  *(uint*)&out[(long)t * 128 + 2*lane] = o;
}

// ---------------------------------------------------------------------------
// host
// ---------------------------------------------------------------------------
extern "C" void kernel_launch(void* const* d_in, const int* in_sizes, int n_in,
                              void* d_out, int out_size, void* d_ws, size_t ws_size,
                              hipStream_t stream) {
  (void)in_sizes; (void)n_in; (void)out_size; (void)ws_size;
  const int*   ids       = (const int*)  d_in[0];
  const float* token_emb = (const float*)d_in[1];
  const float* pos_emb   = (const float*)d_in[2];
  const float* basis_A   = (const float*)d_in[3];
  const float* basis_emb = (const float*)d_in[4];
  const float* q_w  = (const float*)d_in[5];
  const float* q_b  = (const float*)d_in[6];
  const float* k_w  = (const float*)d_in[7];
  const float* k_b  = (const float*)d_in[8];
  const float* ao_w = (const float*)d_in[9];
  const float* ao_b = (const float*)d_in[10];
  const float* recipe  = (const float*)d_in[11];
  const float* ctx_pat = (const float*)d_in[12];
  const float* vout_w  = (const float*)d_in[13];
  const float* vout_b  = (const float*)d_in[14];
  const float* up_w    = (const float*)d_in[15];
  const float* up_b    = (const float*)d_in[16];
  const float* down_w  = (const float*)d_in[17];
  const float* down_b  = (const float*)d_in[18];
  const float* ln1_s = (const float*)d_in[19];
  const float* ln1_b = (const float*)d_in[20];
  const float* ln2_s = (const float*)d_in[21];
  const float* ln2_b = (const float*)d_in[22];
  const float* lnf_s = (const float*)d_in[23];
  const float* lnf_b = (const float*)d_in[24];
  float* out = (float*)d_out;

  float* ws    = (float*)d_ws;
  float* x     = ws;                 // [4096,512] f32
  float* finb  = x + 2097152;        // [4096,256] f32
  float* recsm = finb + 1048576;     // [4,256,32] f32
  float* gate  = recsm + 32768;      // [4,256] f32
  float* qkb   = gate + 1024;        // [4,1024] f32
  ushort* u = (ushort*)(qkb + 4096);
  ushort* nrmh    = u; u += 2097152;    // [4096,512]
  ushort* vsemh   = u; u += 524288;     // [4096,128]
  ushort* Bcat    = u; u += 11010048;   // [4][5376,512]
  ushort* aowh    = u; u += 1048576;    // [4,512,512]
  ushort* voutwh  = u; u += 262144;     // [4,512,128]
  ushort* upwh    = u; u += 4194304;    // [4,2048,512]
  ushort* downwh  = u; u += 4194304;    // [4,512,2048]
  ushort* tembh   = u; u += 16384000;   // [32000,512]

  ushort* XAb = (ushort*)out;              // [4096,4096] @ 0
  ushort* HF  = (ushort*)out;              // [4096,2048] @ 0
  ushort* qkh = (ushort*)out + 16777216;   // [4096,1024]
  ushort* vvh = (ushort*)out + 20971520;   // [4096,512]
  ushort* aoh = (ushort*)out + 23068672;   // [4096,512]

  cvt_all<<<13762, 256, 0, stream>>>(q_w, k_w, ao_w, vout_w, up_w, down_w,
      token_emb, q_b, k_b, Bcat, aowh, voutwh, upwh, downwh, tembh, qkb);
  transpose_basisA<<<dim3(32, 8, 4), 256, 0, stream>>>(basis_A, Bcat);
  precompute_kernel<<<1024, 64, 0, stream>>>(recipe, basis_emb, ctx_pat, recsm, Bcat, gate);
  embed_ln<<<1024, 256, 0, stream>>>(ids, token_emb, pos_emb, ln1_s, ln1_b, x, nrmh);

  for (int l = 0; l < 4; l++) {
    if (l) ln_kernel<<<1024, 256, 0, stream>>>(x, nrmh, ln1_s + l*512, ln1_b + l*512);
    megag1<<<dim3(42, 32), 256, 0, stream>>>(nrmh, Bcat + (long)l*2752512,
        finb, qkh, XAb, gate + l*256, qkb + l*1024);
    topkvsem_kernel<<<1024, 256, 0, stream>>>(finb, recsm + (long)l*8192, XAb, vsemh);
    // Vv: m-stripe 32
    gemmT<32,1><<<dim3(4, 128), 256, 0, stream>>>(vsemh, voutwh + (long)l*65536, vvh,
        vout_b + l*512, 128, 128, 128, 512, 1.f, 32);
    flash_kernel<<<dim3(8, 32), 256, 0, stream>>>(qkh, vvh, aoh);
    // ao proj: m-stripe 32, scalar residual epilogue
    gemmT<32,3><<<dim3(4, 128), 256, 0, stream>>>(aoh, aowh + (long)l*262144, x,
        ao_b + l*512, 512, 512, 512, 512, 1.f, 32);
    ln_kernel<<<1024, 256, 0, stream>>>(x, nrmh, ln2_s + l*512, ln2_b + l*512);
    // up: BM=64, grid (16,64)=1024 wg (4 blocks/CU), m-stripe 16 (R11-measured best)
    gemmT<64,2><<<dim3(16, 64), 256, 0, stream>>>(nrmh, upwh + (long)l*1048576, (void*)HF,
        up_b + l*2048, 512, 512, 512, 2048, 1.f, 16);
    // down: m-stripe 32, scalar residual epilogue
    gemmT<32,3><<<dim3(4, 128), 256, 0, stream>>>(HF, downwh + (long)l*1048576, x,
        down_b + l*512, 2048, 2048, 2048, 512, 1.f, 32);
  }

  ln_kernel<<<1024, 256, 0, stream>>>(x, nrmh, lnf_s, lnf_b);
  // logits: n-band of 25, quarter-tile coalesced NT epilogue, Cs aliased (32KB LDS)
  gemmT<128,4><<<dim3(250, 32), 256, 0, stream>>>(nrmh, tembh, out, nullptr,
      512, 512, 512, 32000, 1.f, -25);
}

// Round 14
// 1040.240 us; speedup vs baseline: 1.0145x; 1.0018x over previous
//
#include <hip/hip_runtime.h>
#include <hip/hip_bf16.h>
#include <math.h>

typedef __attribute__((ext_vector_type(8))) short short8;
typedef __attribute__((ext_vector_type(4))) short short4v;
typedef __attribute__((ext_vector_type(8))) __bf16 bf16x8;
typedef __attribute__((ext_vector_type(4))) float f32x4;
typedef unsigned short ushort;
typedef unsigned int uint;

#define DEVI static __device__ __forceinline__

DEVI ushort f2bf(float f) {
  union { float f; unsigned u; } v; v.f = f;
  unsigned r = v.u + 0x7fffu + ((v.u >> 16) & 1u);
  return (ushort)(r >> 16);
}
DEVI float bf2f(ushort h) {
  union { unsigned u; float f; } v; v.u = (unsigned)h << 16; return v.f;
}
DEVI void gload16(const void* g, void* l) {
  __builtin_amdgcn_global_load_lds((const __attribute__((address_space(1))) void*)g,
                                   (__attribute__((address_space(3))) void*)l, 16, 0, 0);
}

// Block-order mapping: XCD swizzle, then row-major / m-stripe / n-band.
DEVI void map_block(int gx, int gy, int BM, int bmode, int& n0, int& m0) {
  const int nwg = gx * gy;
  const int orig = blockIdx.y * gx + blockIdx.x;
  const int qq = nwg >> 3, rr = nwg & 7;
  const int xcd = orig & 7, sidx = orig >> 3;
  const int wg = (xcd < rr ? xcd * (qq + 1) : rr * (qq + 1) + (xcd - rr) * qq) + sidx;
  if (bmode == 0) {
    n0 = (wg % gx) * 128; m0 = (wg / gx) * BM;
  } else if (bmode > 0) {
    const int mh = bmode, bs = gx * mh;
    const int band = wg / bs, wi = wg - band * bs;
    n0 = (wi / mh) * 128;
    m0 = (band * mh + wi % mh) * BM;
  } else {
    const int bn = -bmode, gm = gy, bs = bn * gm;
    const int band = wg / bs, wi = wg - band * bs;
    m0 = (wi / bn) * BM;
    n0 = (band * bn + wi % bn) * 128;
  }
}

// ---------------------------------------------------------------------------
// BMx128 bf16 MFMA GEMM, BK=64. A [M,K] bf16, B [N,K] bf16 (B^T).
// EPI: 1=bf16 store, 2=GELU->bf16, 3=f32 residual add (scalar, sector-aligned),
//      4=f32 NT store (quarter-tile LDS transpose; Cs aliased onto As).
// ---------------------------------------------------------------------------
template<int BM, int EPI>
__global__ __launch_bounds__(256) void gemmT(
    const ushort* __restrict__ A, const ushort* __restrict__ B,
    void* __restrict__ Cv, const float* __restrict__ bias,
    int K, int lda, int ldb, int ldc, float scale, int bmode)
{
  constexpr int BK = 64;
  constexpr int MF = (BM + 31) / 32;
  constexpr int MH = BM / 2;
  constexpr int ACH = BM * BK / 2048;
  constexpr int BCH = 128 * BK / 2048;
  __shared__ ushort As[BM * BK];
  __shared__ ushort Bs[128 * BK];

  int n0, m0;
  map_block(gridDim.x, gridDim.y, BM, bmode, n0, m0);

  const int tid = threadIdx.x;
  const int lane = tid & 63, wv = tid >> 6;
  const int wm = wv >> 1, wn = wv & 1;
  const int l16 = lane & 15, lq = lane >> 4;

  f32x4 acc[MF][4];
#pragma unroll
  for (int i = 0; i < MF; i++)
#pragma unroll
    for (int j = 0; j < 4; j++) acc[i][j] = (f32x4){0.f, 0.f, 0.f, 0.f};

  const char* apS[ACH]; const char* bpS[BCH];
#pragma unroll
  for (int s = 0; s < ACH; s++) {
    int c = tid + 256 * s;
    apS[s] = (const char*)(A + (long)(m0 + (c >> 3)) * lda) + ((c & 7) << 4);
  }
#pragma unroll
  for (int s = 0; s < BCH; s++) {
    int c = tid + 256 * s;
    bpS[s] = (const char*)(B + (long)(n0 + (c >> 3)) * ldb) + ((c & 7) << 4);
  }

  for (int k0 = 0; k0 < K; k0 += BK) {
    const long kb = (long)k0 * 2;
#pragma unroll
    for (int s = 0; s < ACH; s++) gload16(apS[s] + kb, (char*)As + (tid + 256*s) * 16);
#pragma unroll
    for (int s = 0; s < BCH; s++) gload16(bpS[s] + kb, (char*)Bs + (tid + 256*s) * 16);
    __syncthreads();
#pragma unroll
    for (int ks = 0; ks < 2; ks++) {
      bf16x8 af[MF], bfr[4];
#pragma unroll
      for (int i = 0; i < MF; i++)
        af[i] = __builtin_bit_cast(bf16x8, *(const short8*)&As[(wm*MH + i*16 + l16)*BK + ks*32 + lq*8]);
#pragma unroll
      for (int j = 0; j < 4; j++)
        bfr[j] = __builtin_bit_cast(bf16x8, *(const short8*)&Bs[(wn*64 + j*16 + l16)*BK + ks*32 + lq*8]);
#pragma unroll
      for (int i = 0; i < MF; i++)
#pragma unroll
        for (int j = 0; j < 4; j++)
          acc[i][j] = __builtin_amdgcn_mfma_f32_16x16x32_bf16(af[i], bfr[j], acc[i][j], 0, 0, 0);
    }
    __syncthreads();
  }

  float* Cf = (float*)Cv;
  ushort* Ch = (ushort*)Cv;

  if (EPI == 4) {
    // quarter-tile (16 rows) LDS transpose; NT f32x4 stores, 512B/row contiguous.
    float* Cs = (float*)As;
    const int er = tid >> 5, ec = (tid & 31) << 2;
#pragma unroll
    for (int half = 0; half < 2; half++)
#pragma unroll
      for (int i = 0; i < MF; i++) {
        __syncthreads();
        if (wm == half) {
#pragma unroll
          for (int j = 0; j < 4; j++) {
            const int col = wn*64 + j*16 + l16;
            const float cb = bias ? bias[n0 + col] : 0.f;
#pragma unroll
            for (int t = 0; t < 4; t++)
              Cs[(lq*4 + t)*132 + col] = acc[i][j][t] * scale + cb;
          }
        }
        __syncthreads();
#pragma unroll
        for (int ps = 0; ps < 2; ps++) {
          const int row = ps*8 + er;
          f32x4 v = *(const f32x4*)&Cs[row*132 + ec];
          __builtin_nontemporal_store(v,
              (f32x4*)(Cf + (long)(m0 + half*MH + i*16 + row) * ldc + n0 + ec));
        }
      }
  } else {
#pragma unroll
    for (int i = 0; i < MF; i++) {
      const int row0 = m0 + wm*MH + i*16 + lq*4;
#pragma unroll
      for (int j = 0; j < 4; j++) {
        const int col = n0 + wn*64 + j*16 + l16;
        const float cb = bias ? bias[col] : 0.f;
#pragma unroll
        for (int t = 0; t < 4; t++) {
          float val = acc[i][j][t] * scale + cb;
          const long idx = (long)(row0 + t) * ldc + col;
          if (EPI == 1)      Ch[idx] = f2bf(val);
          else if (EPI == 2) { val = 0.5f * val * (1.f + erff(val * 0.70710678118654752f)); Ch[idx] = f2bf(val); }
          else               Cf[idx] += val;
        }
      }
    }
  }
}

// ---------------------------------------------------------------------------
// Mega GEMM (BK=64): A=nrm [4096,512], B=Bcat[l] [1280,512] (256 emb_sem |
// 512 q_w | 512 k_w) + shared bA=[32*128,512] basisAT for cols >= 1280.
// Grid (42,32). n0=1280 is an exact tile boundary.
// ---------------------------------------------------------------------------
__global__ __launch_bounds__(256) void megag1(
    const ushort* __restrict__ A, const ushort* __restrict__ B,
    const ushort* __restrict__ bA,
    ushort* __restrict__ finbh, ushort* __restrict__ qkh, ushort* __restrict__ XAb,
    const float* __restrict__ gate, const float* __restrict__ qkbias)
{
  constexpr int BK = 64;
  __shared__ ushort As[128 * BK];
  __shared__ ushort Bs[128 * BK];
  int n0, m0;
  map_block(gridDim.x, gridDim.y, 128, 8, n0, m0);

  const int tid = threadIdx.x;
  const int lane = tid & 63, wv = tid >> 6;
  const int wm = wv >> 1, wn = wv & 1;
  const int l16 = lane & 15, lq = lane >> 4;

  f32x4 acc[4][4];
#pragma unroll
  for (int i = 0; i < 4; i++)
#pragma unroll
    for (int j = 0; j < 4; j++) acc[i][j] = (f32x4){0.f, 0.f, 0.f, 0.f};

  const ushort* Bbase = (n0 < 1280) ? (B + (long)n0 * 512)
                                    : (bA + (long)(n0 - 1280) * 512);
  const char* apS[4]; const char* bpS[4];
#pragma unroll
  for (int s = 0; s < 4; s++) {
    int c = tid + 256 * s;
    apS[s] = (const char*)(A + (long)(m0 + (c >> 3)) * 512) + ((c & 7) << 4);
    bpS[s] = (const char*)(Bbase + (long)(c >> 3) * 512) + ((c & 7) << 4);
  }

  for (int k0 = 0; k0 < 512; k0 += BK) {
    const long kb = (long)k0 * 2;
#pragma unroll
    for (int s = 0; s < 4; s++) {
      gload16(apS[s] + kb, (char*)As + (tid + 256*s) * 16);
      gload16(bpS[s] + kb, (char*)Bs + (tid + 256*s) * 16);
    }
    __syncthreads();
#pragma unroll
    for (int ks = 0; ks < 2; ks++) {
      bf16x8 af[4], bfr[4];
#pragma unroll
      for (int i = 0; i < 4; i++) {
        af[i]  = __builtin_bit_cast(bf16x8, *(const short8*)&As[(wm*64 + i*16 + l16)*BK + ks*32 + lq*8]);
        bfr[i] = __builtin_bit_cast(bf16x8, *(const short8*)&Bs[(wn*64 + i*16 + l16)*BK + ks*32 + lq*8]);
      }
#pragma unroll
      for (int i = 0; i < 4; i++)
#pragma unroll
        for (int j = 0; j < 4; j++)
          acc[i][j] = __builtin_amdgcn_mfma_f32_16x16x32_bf16(af[i], bfr[j], acc[i][j], 0, 0, 0);
    }
    __syncthreads();
  }

#pragma unroll
  for (int i = 0; i < 4; i++) {
    const int row0 = m0 + wm*64 + i*16 + lq*4;
#pragma unroll
    for (int j = 0; j < 4; j++) {
      const int col = n0 + wn*64 + j*16 + l16;
      if (col < 256) {
        const float g = gate[col];
#pragma unroll
        for (int t = 0; t < 4; t++) finbh[(long)(row0 + t) * 256 + col] = f2bf(acc[i][j][t] * g);
      } else if (col < 1280) {
        const int c = col - 256;
        const float bb = qkbias[c];
#pragma unroll
        for (int t = 0; t < 4; t++) qkh[(long)(row0 + t) * 1024 + c] = f2bf(acc[i][j][t] + bb);
      } else {
        const int c = col - 1280;
#pragma unroll
        for (int t = 0; t < 4; t++) XAb[(long)(row0 + t) * 4096 + c] = f2bf(acc[i][j][t]);
      }
    }
  }
}

// ---------------------------------------------------------------------------
// Fused causal flash attention, balanced q-tile pairs {p, 15-p} per block.
// Grid (8, 32). Double-buffered K/V staging.
// ---------------------------------------------------------------------------
__global__ __launch_bounds__(256) void flash_kernel(
    const ushort* __restrict__ qk, const ushort* __restrict__ v,
    ushort* __restrict__ o)
{
  __shared__ ushort Ks[2][4096];
  __shared__ ushort VTs[2][4096];
  __shared__ ushort Ps[4096];
  const int p = blockIdx.x, bh = blockIdx.y;
  const int b = bh >> 3, h = bh & 7;
  const int tid = threadIdx.x, lane = tid & 63, w = tid >> 6;
  const int l16 = lane & 15, lq = lane >> 4;
  const long tokbase = (long)b * 1024;
  const ushort* Qbase = qk + tokbase * 1024 + h * 64;
  const char*   Kbase = (const char*)(qk + tokbase * 1024 + 512 + h * 64);
  const ushort* Vbase = v + tokbase * 512 + h * 64;

  const int krow = tid >> 3, kcb = (tid & 7) << 4;
  const int vkv  = tid >> 2, vdb = (tid & 3) << 4;
  const int kswz = kcb ^ ((krow & 7) << 4);

#pragma unroll 1
  for (int half = 0; half < 2; half++) {
    const int qt = half ? (15 - p) : p;
    const int q0 = qt * 64;
    const int ntiles = qt + 1;

    const ushort* qrow = Qbase + (long)(q0 + w*16 + l16) * 1024;
    const bf16x8 qf0 = *(const bf16x8*)(qrow + lq*8);
    const bf16x8 qf1 = *(const bf16x8*)(qrow + 32 + lq*8);

    float m_[4] = {-1e30f, -1e30f, -1e30f, -1e30f};
    float l_[4] = {0.f, 0.f, 0.f, 0.f};
    f32x4 od[4];
#pragma unroll
    for (int dt = 0; dt < 4; dt++) od[dt] = (f32x4){0.f, 0.f, 0.f, 0.f};

    gload16(Kbase + (long)krow * 2048 + kswz, (char*)Ks[0] + tid * 16);
    gload16(Kbase + (long)(32 + krow) * 2048 + kswz, (char*)Ks[0] + 4096 + tid * 16);
    {
      const ushort* vr = Vbase + (long)vkv * 512 + vdb;
      short8 va = *(const short8*)vr;
      short8 vb = *(const short8*)(vr + 8);
#pragma unroll
      for (int j = 0; j < 8; j++) {
        int d1 = vdb + j, d2 = vdb + 8 + j;
        *(ushort*)((char*)VTs[0] + d1*128 + ((vkv*2) ^ ((d1 & 7) << 4))) = (ushort)va[j];
        *(ushort*)((char*)VTs[0] + d2*128 + ((vkv*2) ^ ((d2 & 7) << 4))) = (ushort)vb[j];
      }
    }
    __syncthreads();

    int cur = 0;
#pragma unroll 1
    for (int t = 0; t < ntiles; t++) {
      const bool hasn = (t + 1 < ntiles);
      short8 vaN, vbN;
      if (hasn) {
        const long n0g = (long)(t + 1) * 64;
        gload16(Kbase + (n0g + krow) * 2048 + kswz, (char*)Ks[cur ^ 1] + tid * 16);
        gload16(Kbase + (n0g + 32 + krow) * 2048 + kswz, (char*)Ks[cur ^ 1] + 4096 + tid * 16);
        const ushort* vr = Vbase + (n0g + vkv) * 512 + vdb;
        vaN = *(const short8*)vr;
        vbN = *(const short8*)(vr + 8);
      }

      f32x4 sa[4];
#pragma unroll
      for (int n = 0; n < 4; n++) sa[n] = (f32x4){0.f, 0.f, 0.f, 0.f};
#pragma unroll
      for (int ks = 0; ks < 2; ks++) {
        const bf16x8 qf = ks ? qf1 : qf0;
#pragma unroll
        for (int n = 0; n < 4; n++) {
          const int row = n*16 + l16;
          bf16x8 kf = *(const bf16x8*)((const char*)Ks[cur] + row*128 + ((ks*64 + lq*16) ^ ((row & 7) << 4)));
          sa[n] = __builtin_amdgcn_mfma_f32_16x16x32_bf16(qf, kf, sa[n], 0, 0, 0);
        }
      }

      const bool diag = (t == qt);
      float rowmax[4] = {-1e30f, -1e30f, -1e30f, -1e30f};
#pragma unroll
      for (int n = 0; n < 4; n++)
#pragma unroll
        for (int r = 0; r < 4; r++) {
          float sv = sa[n][r] * 0.125f;
          if (diag && (n*16 + l16 > w*16 + lq*4 + r)) sv = -1e30f;
          sa[n][r] = sv;
          rowmax[r] = fmaxf(rowmax[r], sv);
        }
#pragma unroll
      for (int r = 0; r < 4; r++)
#pragma unroll
        for (int off = 8; off; off >>= 1) rowmax[r] = fmaxf(rowmax[r], __shfl_xor(rowmax[r], off));

      float psum[4];
#pragma unroll
      for (int r = 0; r < 4; r++) {
        const float mn = fmaxf(m_[r], rowmax[r]);
        const float corr = __expf(m_[r] - mn);
        m_[r] = mn;
        l_[r] *= corr;
#pragma unroll
        for (int dt = 0; dt < 4; dt++) od[dt][r] *= corr;
        psum[r] = 0.f;
      }
#pragma unroll
      for (int n = 0; n < 4; n++)
#pragma unroll
        for (int r = 0; r < 4; r++) {
          const float pv = __expf(sa[n][r] - m_[r]);
          psum[r] += pv;
          const int prow = w*16 + lq*4 + r;
          *(ushort*)((char*)Ps + prow*128 + (((n*16 + l16)*2) ^ ((prow & 7) << 4))) = f2bf(pv);
        }
#pragma unroll
      for (int r = 0; r < 4; r++) {
#pragma unroll
        for (int off = 8; off; off >>= 1) psum[r] += __shfl_xor(psum[r], off);
        l_[r] += psum[r];
      }

#pragma unroll
      for (int ks = 0; ks < 2; ks++) {
        const int prow = w*16 + l16;
        bf16x8 pf = *(const bf16x8*)((const char*)Ps + prow*128 + ((ks*64 + lq*16) ^ ((prow & 7) << 4)));
#pragma unroll
        for (int dt = 0; dt < 4; dt++) {
          const int vrow = dt*16 + l16;
          bf16x8 vf = *(const bf16x8*)((const char*)VTs[cur] + vrow*128 + ((ks*64 + lq*16) ^ ((vrow & 7) << 4)));
          od[dt] = __builtin_amdgcn_mfma_f32_16x16x32_bf16(pf, vf, od[dt], 0, 0, 0);
        }
      }

      if (hasn) {
#pragma unroll
        for (int j = 0; j < 8; j++) {
          int d1 = vdb + j, d2 = vdb + 8 + j;
          *(ushort*)((char*)VTs[cur ^ 1] + d1*128 + ((vkv*2) ^ ((d1 & 7) << 4))) = (ushort)vaN[j];
          *(ushort*)((char*)VTs[cur ^ 1] + d2*128 + ((vkv*2) ^ ((d2 & 7) << 4))) = (ushort)vbN[j];
        }
      }
      __syncthreads();
      cur ^= 1;
    }

#pragma unroll
    for (int r = 0; r < 4; r++) {
      const float inv = 1.f / l_[r];
      ushort* orow = o + (tokbase + q0 + w*16 + lq*4 + r) * 512 + h * 64 + l16;
#pragma unroll
      for (int dt = 0; dt < 4; dt++) orow[dt*16] = f2bf(od[dt][r] * inv);
    }
  }
}

// ---------------------------------------------------------------------------
// One-shot conversion kernel (all weights + qk bias merge).
// ---------------------------------------------------------------------------
DEVI void cvt8(const float* s, ushort* d) {
  float4 u = *(const float4*)s, v = *(const float4*)(s + 4);
  short8 o;
  o[0]=(short)f2bf(u.x); o[1]=(short)f2bf(u.y); o[2]=(short)f2bf(u.z); o[3]=(short)f2bf(u.w);
  o[4]=(short)f2bf(v.x); o[5]=(short)f2bf(v.y); o[6]=(short)f2bf(v.z); o[7]=(short)f2bf(v.w);
  *(short8*)d = o;
}
__global__ __launch_bounds__(256) void cvt_all(
    const float* __restrict__ q_w, const float* __restrict__ k_w,
    const float* __restrict__ ao_w, const float* __restrict__ vout_w,
    const float* __restrict__ up_w, const float* __restrict__ down_w,
    const float* __restrict__ temb, const float* __restrict__ q_b,
    const float* __restrict__ k_b,
    ushort* __restrict__ Bcat, ushort* __restrict__ aowh, ushort* __restrict__ voutwh,
    ushort* __restrict__ upwh, ushort* __restrict__ downwh, ushort* __restrict__ tembh,
    float* __restrict__ qkb)
{
  long u = (long)blockIdx.x * 256 + threadIdx.x;
  if (u < 262144) {                    // q_w/k_w -> Bcat rows 256..1279 per layer
    long e = u * 8;
    int l = (int)(e >> 19);
    long rem = e & 524287;
    bool isk = rem >= 262144;
    long so = rem & 262143;
    cvt8((isk ? k_w : q_w) + (long)l * 262144 + so,
         Bcat + (long)l * 655360 + 131072 + (isk ? 262144 : 0) + so);
    return;
  }
  u -= 262144;
  if (u < 131072) { cvt8(ao_w + u*8, aowh + u*8); return; }
  u -= 131072;
  if (u < 32768)  { cvt8(vout_w + u*8, voutwh + u*8); return; }
  u -= 32768;
  if (u < 524288) { cvt8(up_w + u*8, upwh + u*8); return; }
  u -= 524288;
  if (u < 524288) { cvt8(down_w + u*8, downwh + u*8); return; }
  u -= 524288;
  if (u < 2048000){ cvt8(temb + u*8, tembh + u*8); return; }
  u -= 2048000;
  {
    long i8 = u * 8;
    int l = (int)(i8 >> 10), c = (int)(i8 & 1023);
    const float* src = (c < 512) ? (q_b + l*512 + c) : (k_b + l*512 + c - 512);
    float* dst = qkb + i8;
    *(float4*)dst = *(const float4*)src;
    *(float4*)(dst + 4) = *(const float4*)(src + 4);
  }
}

// basis_A [32][512][128] f32 -> basisAT [32][128][512] bf16 (single shared copy)
__global__ __launch_bounds__(256) void transpose_basisA(
    const float* __restrict__ src, ushort* __restrict__ dst)
{
  __shared__ ushort tile[64][132];
  const int n = blockIdx.x;
  const int d0 = blockIdx.y * 64;
  const int tid = threadIdx.x;
#pragma unroll
  for (int it = 0; it < 8; it++) {
    int d = it * 8 + (tid >> 5);
    int rr = (tid & 31) * 4;
    float4 v = *(const float4*)(src + ((long)n * 512 + d0 + d) * 128 + rr);
    tile[d][rr + 0] = f2bf(v.x);
    tile[d][rr + 1] = f2bf(v.y);
    tile[d][rr + 2] = f2bf(v.z);
    tile[d][rr + 3] = f2bf(v.w);
  }
  __syncthreads();
#pragma unroll
  for (int it = 0; it < 4; it++) {
    int rr = it * 32 + (tid >> 3);
    int dof = (tid & 7) * 8;
    short8 s;
#pragma unroll
    for (int j = 0; j < 8; j++) s[j] = (short)tile[dof + j][rr];
    *(short8*)(dst + ((long)n * 128 + rr) * 512 + d0 + dof) = s;
  }
}

// embed + LN1(layer0)
__global__ __launch_bounds__(256) void embed_ln(
    const int* __restrict__ ids, const float* __restrict__ tok,
    const float* __restrict__ pos, const float* __restrict__ gam,
    const float* __restrict__ bet, float* __restrict__ x, ushort* __restrict__ outh)
{
  int row = blockIdx.x * 4 + (threadIdx.x >> 6);
  int lane = threadIdx.x & 63;
  int id = ids[row], sp = row & 1023;
  const float* tp = tok + (long)id * 512;
  const float* pp = pos + (long)sp * 512;
  float4 v0 = *(const float4*)(tp + lane*4);
  float4 p0 = *(const float4*)(pp + lane*4);
  float4 v1 = *(const float4*)(tp + 256 + lane*4);
  float4 p1 = *(const float4*)(pp + 256 + lane*4);
  v0.x+=p0.x; v0.y+=p0.y; v0.z+=p0.z; v0.w+=p0.w;
  v1.x+=p1.x; v1.y+=p1.y; v1.z+=p1.z; v1.w+=p1.w;
  *(float4*)(x + (long)row*512 + lane*4) = v0;
  *(float4*)(x + (long)row*512 + 256 + lane*4) = v1;
  float s = v0.x+v0.y+v0.z+v0.w + v1.x+v1.y+v1.z+v1.w;
#pragma unroll
  for (int o = 32; o; o >>= 1) s += __shfl_xor(s, o);
  float mean = s * (1.f/512.f);
  float d0=v0.x-mean, d1=v0.y-mean, d2=v0.z-mean, d3=v0.w-mean;
  float e0=v1.x-mean, e1=v1.y-mean, e2=v1.z-mean, e3=v1.w-mean;
  float qv = d0*d0+d1*d1+d2*d2+d3*d3 + e0*e0+e1*e1+e2*e2+e3*e3;
#pragma unroll
  for (int o = 32; o; o >>= 1) qv += __shfl_xor(qv, o);
  float inv = rsqrtf(qv * (1.f/512.f) + 1e-5f);
  float4 g0 = *(const float4*)(gam + lane*4);
  float4 g1 = *(const float4*)(gam + 256 + lane*4);
  float4 b0 = *(const float4*)(bet + lane*4);
  float4 b1 = *(const float4*)(bet + 256 + lane*4);
  short4v o0, o1;
  o0[0]=(short)f2bf(d0*inv*g0.x + b0.x); o0[1]=(short)f2bf(d1*inv*g0.y + b0.y);
  o0[2]=(short)f2bf(d2*inv*g0.z + b0.z); o0[3]=(short)f2bf(d3*inv*g0.w + b0.w);
  o1[0]=(short)f2bf(e0*inv*g1.x + b1.x); o1[1]=(short)f2bf(e1*inv*g1.y + b1.y);
  o1[2]=(short)f2bf(e2*inv*g1.z + b1.z); o1[3]=(short)f2bf(e3*inv*g1.w + b1.w);
  *(short4v*)(outh + (long)row*512 + lane*4) = o0;
  *(short4v*)(outh + (long)row*512 + 256 + lane*4) = o1;
}

__global__ __launch_bounds__(256) void ln_kernel(
    const float* __restrict__ in, ushort* __restrict__ outh,
    const float* __restrict__ gam, const float* __restrict__ bet)
{
  int row = blockIdx.x * 4 + (threadIdx.x >> 6);
  int lane = threadIdx.x & 63;
  const float* p = in + (long)row * 512;
  float4 v0 = *(const float4*)(p + lane * 4);
  float4 v1 = *(const float4*)(p + 256 + lane * 4);
  float s = v0.x+v0.y+v0.z+v0.w + v1.x+v1.y+v1.z+v1.w;
#pragma unroll
  for (int o = 32; o; o >>= 1) s += __shfl_xor(s, o);
  float mean = s * (1.f/512.f);
  float d0=v0.x-mean, d1=v0.y-mean, d2=v0.z-mean, d3=v0.w-mean;
  float e0=v1.x-mean, e1=v1.y-mean, e2=v1.z-mean, e3=v1.w-mean;
  float qv = d0*d0+d1*d1+d2*d2+d3*d3 + e0*e0+e1*e1+e2*e2+e3*e3;
#pragma unroll
  for (int o = 32; o; o >>= 1) qv += __shfl_xor(qv, o);
  float inv = rsqrtf(qv * (1.f/512.f) + 1e-5f);
  float4 g0 = *(const float4*)(gam + lane*4);
  float4 g1 = *(const float4*)(gam + 256 + lane*4);
  float4 b0 = *(const float4*)(bet + lane*4);
  float4 b1 = *(const float4*)(bet + 256 + lane*4);
  short4v o0, o1;
  o0[0]=(short)f2bf(d0*inv*g0.x + b0.x); o0[1]=(short)f2bf(d1*inv*g0.y + b0.y);
  o0[2]=(short)f2bf(d2*inv*g0.z + b0.z); o0[3]=(short)f2bf(d3*inv*g0.w + b0.w);
  o1[0]=(short)f2bf(e0*inv*g1.x + b1.x); o1[1]=(short)f2bf(e1*inv*g1.y + b1.y);
  o1[2]=(short)f2bf(e2*inv*g1.z + b1.z); o1[3]=(short)f2bf(e3*inv*g1.w + b1.w);
  *(short4v*)(outh + (long)row*512 + lane*4) = o0;
  *(short4v*)(outh + (long)row*512 + 256 + lane*4) = o1;
}

// per (l,n): rec_sm=softmax(recipe), emb_sem(bf16) into Bcat rows 0-255, gate
__global__ __launch_bounds__(64) void precompute_kernel(
    const float* __restrict__ recipe, const float* __restrict__ basis_emb,
    const float* __restrict__ ctx_pat, float* __restrict__ rec_sm,
    ushort* __restrict__ Bcat, float* __restrict__ gate)
{
  int ln = blockIdx.x;
  int l = ln >> 8, n = ln & 255;
  int lane = threadIdx.x;
  const float* r = recipe + (long)ln * 32;
  float rv[32];
  float m = -1e30f;
#pragma unroll
  for (int j = 0; j < 32; j++) { rv[j] = r[j]; m = fmaxf(m, rv[j]); }
  float sum = 0.f;
#pragma unroll
  for (int j = 0; j < 32; j++) { rv[j] = expf(rv[j] - m); sum += rv[j]; }
  float inv = 1.f / sum;
#pragma unroll
  for (int j = 0; j < 32; j++) rv[j] *= inv;
  if (lane < 32) rec_sm[(long)ln * 32 + lane] = rv[lane];
  ushort* dst = Bcat + (long)l * 655360 + (long)n * 512;
#pragma unroll
  for (int cc = 0; cc < 8; cc++) {
    int c = lane + cc * 64;
    float acc = 0.f;
#pragma unroll
    for (int j = 0; j < 32; j++) acc += rv[j] * basis_emb[j * 512 + c];
    dst[c] = f2bf(acc);
  }
  if (lane == 0) {
    float sh = 0.f;
#pragma unroll
    for (int h = 0; h < 8; h++) sh += ctx_pat[(long)ln * 8 + h];
    gate[ln] = 1.f / (1.f + expf(-sh * (1.f/1024.f)));
  }
}

// fused: top-8 + weight softmax + token_recipe + v_sem (bf16 fin, vectorized XA)
__global__ __launch_bounds__(256) void topkvsem_kernel(
    const ushort* __restrict__ finh, const float* __restrict__ rec_sm_l,
    const ushort* __restrict__ XA, ushort* __restrict__ out)
{
  __shared__ float trs[4][32];
  int wv = threadIdx.x >> 6, lane = threadIdx.x & 63;
  int t = blockIdx.x * 4 + wv;
  const ushort* f = finh + (long)t * 256;
  float v0 = bf2f(f[lane]), v1 = bf2f(f[lane+64]), v2 = bf2f(f[lane+128]), v3 = bf2f(f[lane+192]);
  int i0 = lane, i1 = lane+64, i2 = lane+128, i3 = lane+192;
  float topv[8]; int topi[8];
#pragma unroll
  for (int it = 0; it < 8; it++) {
    float bm = v0; int bi = i0;
    if (v1 > bm || (v1 == bm && i1 < bi)) { bm = v1; bi = i1; }
    if (v2 > bm || (v2 == bm && i2 < bi)) { bm = v2; bi = i2; }
    if (v3 > bm || (v3 == bm && i3 < bi)) { bm = v3; bi = i3; }
#pragma unroll
    for (int o = 32; o; o >>= 1) {
      float om = __shfl_xor(bm, o);
      int oi = __shfl_xor(bi, o);
      if (om > bm || (om == bm && oi < bi)) { bm = om; bi = oi; }
    }
    topv[it] = bm; topi[it] = bi;
    if (i0 == bi) v0 = -1e30f;
    if (i1 == bi) v1 = -1e30f;
    if (i2 == bi) v2 = -1e30f;
    if (i3 == bi) v3 = -1e30f;
  }
  float w[8], wsum = 0.f;
#pragma unroll
  for (int k = 0; k < 8; k++) { w[k] = expf(topv[k] - topv[0]); wsum += w[k]; }
  float winv = 1.f / wsum;
  if (lane < 32) {
    float acc = 0.f;
#pragma unroll
    for (int k = 0; k < 8; k++)
      acc += (w[k] * winv) * rec_sm_l[(long)topi[k] * 32 + lane];
    trs[wv][lane] = acc;
  }
  __syncthreads();
  const ushort* xa = XA + (long)t * 4096;
  float a0 = 0.f, a1 = 0.f;
#pragma unroll
  for (int n = 0; n < 32; n++) {
    float wn = trs[wv][n];
    uint u = *(const uint*)&xa[n*128 + 2*lane];
    a0 += wn * bf2f((ushort)(u & 0xffffu));
    a1 += wn * bf2f((ushort)(u >> 16));
  }
  uint o = (uint)f2bf(a0) | ((uint)f2bf(a1) << 16);
  *(uint*)&out[(long)t * 128 + 2*lane] = o;
}

// ---------------------------------------------------------------------------
// host
// ---------------------------------------------------------------------------
extern "C" void kernel_launch(void* const* d_in, const int* in_sizes, int n_in,
                              void* d_out, int out_size, void* d_ws, size_t ws_size,
                              hipStream_t stream) {
  (void)in_sizes; (void)n_in; (void)out_size; (void)ws_size;
  const int*   ids       = (const int*)  d_in[0];
  const float* token_emb = (const float*)d_in[1];
  const float* pos_emb   = (const float*)d_in[2];
  const float* basis_A   = (const float*)d_in[3];
  const float* basis_emb = (const float*)d_in[4];
  const float* q_w  = (const float*)d_in[5];
  const float* q_b  = (const float*)d_in[6];
  const float* k_w  = (const float*)d_in[7];
  const float* k_b  = (const float*)d_in[8];
  const float* ao_w = (const float*)d_in[9];
  const float* ao_b = (const float*)d_in[10];
  const float* recipe  = (const float*)d_in[11];
  const float* ctx_pat = (const float*)d_in[12];
  const float* vout_w  = (const float*)d_in[13];
  const float* vout_b  = (const float*)d_in[14];
  const float* up_w    = (const float*)d_in[15];
  const float* up_b    = (const float*)d_in[16];
  const float* down_w  = (const float*)d_in[17];
  const float* down_b  = (const float*)d_in[18];
  const float* ln1_s = (const float*)d_in[19];
  const float* ln1_b = (const float*)d_in[20];
  const float* ln2_s = (const float*)d_in[21];
  const float* ln2_b = (const float*)d_in[22];
  const float* lnf_s = (const float*)d_in[23];
  const float* lnf_b = (const float*)d_in[24];
  float* out = (float*)d_out;

  float* ws    = (float*)d_ws;
  float* x     = ws;                 // [4096,512] f32
  float* recsm = x + 2097152;        // [4,256,32] f32
  float* gate  = recsm + 32768;      // [4,256] f32
  float* qkb   = gate + 1024;        // [4,1024] f32
  ushort* u = (ushort*)(qkb + 4096);
  ushort* nrmh    = u; u += 2097152;    // [4096,512]
  ushort* vsemh   = u; u += 524288;     // [4096,128]
  ushort* finbh   = u; u += 1048576;    // [4096,256] bf16
  ushort* Bcat    = u; u += 2621440;    // [4][1280,512]
  ushort* basisAT = u; u += 2097152;    // [32*128,512] shared
  ushort* aowh    = u; u += 1048576;    // [4,512,512]
  ushort* voutwh  = u; u += 262144;     // [4,512,128]
  ushort* upwh    = u; u += 4194304;    // [4,2048,512]
  ushort* downwh  = u; u += 4194304;    // [4,512,2048]
  ushort* tembh   = u; u += 16384000;   // [32000,512]

  ushort* XAb = (ushort*)out;              // [4096,4096] @ 0
  ushort* HF  = (ushort*)out;              // [4096,2048] @ 0
  ushort* qkh = (ushort*)out + 16777216;   // [4096,1024]
  ushort* vvh = (ushort*)out + 20971520;   // [4096,512]
  ushort* aoh = (ushort*)out + 23068672;   // [4096,512]

  cvt_all<<<13762, 256, 0, stream>>>(q_w, k_w, ao_w, vout_w, up_w, down_w,
      token_emb, q_b, k_b, Bcat, aowh, voutwh, upwh, downwh, tembh, qkb);
  transpose_basisA<<<dim3(32, 8), 256, 0, stream>>>(basis_A, basisAT);
  precompute_kernel<<<1024, 64, 0, stream>>>(recipe, basis_emb, ctx_pat, recsm, Bcat, gate);
  embed_ln<<<1024, 256, 0, stream>>>(ids, token_emb, pos_emb, ln1_s, ln1_b, x, nrmh);

  for (int l = 0; l < 4; l++) {
    if (l) ln_kernel<<<1024, 256, 0, stream>>>(x, nrmh, ln1_s + l*512, ln1_b + l*512);
    megag1<<<dim3(42, 32), 256, 0, stream>>>(nrmh, Bcat + (long)l*655360, basisAT,
        finbh, qkh, XAb, gate + l*256, qkb + l*1024);
    topkvsem_kernel<<<1024, 256, 0, stream>>>(finbh, recsm + (long)l*8192, XAb, vsemh);
    // Vv: m-stripe 32
    gemmT<32,1><<<dim3(4, 128), 256, 0, stream>>>(vsemh, voutwh + (long)l*65536, vvh,
        vout_b + l*512, 128, 128, 128, 512, 1.f, 32);
    flash_kernel<<<dim3(8, 32), 256, 0, stream>>>(qkh, vvh, aoh);
    // ao proj: m-stripe 32, scalar residual epilogue
    gemmT<32,3><<<dim3(4, 128), 256, 0, stream>>>(aoh, aowh + (long)l*262144, x,
        ao_b + l*512, 512, 512, 512, 512, 1.f, 32);
    ln_kernel<<<1024, 256, 0, stream>>>(x, nrmh, ln2_s + l*512, ln2_b + l*512);
    // up: BM=64, grid (16,64), m-stripe 16
    gemmT<64,2><<<dim3(16, 64), 256, 0, stream>>>(nrmh, upwh + (long)l*1048576, (void*)HF,
        up_b + l*2048, 512, 512, 512, 2048, 1.f, 16);
    // down: m-stripe 32, scalar residual epilogue
    gemmT<32,3><<<dim3(4, 128), 256, 0, stream>>>(HF, downwh + (long)l*1048576, x,
        down_b + l*512, 2048, 2048, 2048, 512, 1.f, 32);
  }

  ln_kernel<<<1024, 256, 0, stream>>>(x, nrmh, lnf_s, lnf_b);
  // logits: n-band of 25, quarter-tile coalesced NT epilogue
  gemmT<128,4><<<dim3(250, 32), 256, 0, stream>>>(nrmh, tembh, out, nullptr,
      512, 512, 512, 32000, 1.f, -25);
}